// Round 1
// baseline (5518.198 us; speedup 1.0000x reference)
//
#include <hip/hip_runtime.h>
#include <hip/hip_bf16.h>

// LightGCN forward on MI355X — round 10.
// r9 evidence: spmm_csr 107us/layer (VALU 51%, HBM 45%, FETCH 355MB); non-spmm
//   kernels ~312us of the 526 total (3 preprocessing passes over 51MB edges).
// r10: row-exact sort ELIMINATED. scatter2 bins by (128-row block x 8192-col
//   region); SpMM accumulates into a 32KB LDS f32 tile via ds_add_f32 and
//   sweeps col regions in phase across all 1184 co-resident blocks (per-XCD L2
//   working set ~1MB -> gather fetch should ~halve). Sampled layer 3 via
//   slot_of_row table + per-bucket filtered scan. C aliases A; ws req shrinks.

#define N_USERS  100000
#define N_ITEMS  50000
#define N_TOTAL  150000          // N_USERS + N_ITEMS
#define D        64
#define NNZ      6400000
#define BATCH    4096
#define NELEM    (N_TOTAL * D)   // 9,600,000
#define CHUNK    8192
#define EB       ((NNZ + CHUNK - 1) / CHUNK)  // 782

#define NC       37              // coarse buckets (4096 rows each)
#define CROWS    4096
#define CAPC     180224          // coarse capacity = mean 174763 + 13 sigma
#define NCH2     (CAPC / CHUNK)  // 22 chunks per coarse region
#define NF       32              // fine row-blocks per coarse (128 rows each)
#define RPB      128
#define NFB      (NC * NF)       // 1184 fine buckets (row blocks)
#define NREG     19              // col regions of 8192 cols (1MB bf16 slice)
#define NSUB     (NFB * NREG)    // 22496 sub-buckets
#define CAPS     416             // sub-bucket capacity = mean 298 + 6.8 sigma

__device__ __forceinline__ float bf2f(unsigned short h) {
    return __uint_as_float(((unsigned int)h) << 16);
}

// ---------- zero cursors ----------
__global__ void lgcn_zero(int* __restrict__ cur1, int* __restrict__ cur2) {
    int i = blockIdx.x * blockDim.x + threadIdx.x;
    if (i < NC) cur1[i] = 0;
    if (i < NSUB) cur2[i] = 0;
}

// ---------- pass 1: COO -> 37 coarse buckets, direct scatter ----------
// X pair: x = (row_in_coarse<<18) | col  (12b + 18b), y = val bits
__global__ void __launch_bounds__(256)
lgcn_scatter1(const int*   __restrict__ rows,
              const int*   __restrict__ cols,
              const float* __restrict__ vals,
              int*         __restrict__ cur1,
              int2*        __restrict__ X) {
    __shared__ int h[NC];
    __shared__ int gb[NC];
    int tid = threadIdx.x;
    int s = blockIdx.x * CHUNK;
    int e_end = s + CHUNK; if (e_end > NNZ) e_end = NNZ;

    if (tid < NC) h[tid] = 0;
    __syncthreads();
    for (int e = s + tid; e < e_end; e += 256)
        atomicAdd(&h[rows[e] >> 12], 1);
    __syncthreads();
    if (tid < NC) {
        int c = h[tid];
        gb[tid] = c ? atomicAdd(&cur1[tid], c) : 0;
        h[tid] = 0;
    }
    __syncthreads();
    for (int e = s + tid; e < e_end; e += 256) {
        int r = rows[e];
        int c = r >> 12;
        int rank = atomicAdd(&h[c], 1);
        int o = gb[c] + rank;
        int2 p;
        p.x = ((r & 4095) << 18) | cols[e];
        p.y = __float_as_int(vals[e]);
        X[(o < CAPC) ? ((size_t)c * CAPC + o) : ((size_t)NC * CAPC)] = p;
    }
}

// ---------- pass 2: coarse region -> (fine-row x col-region) sub-buckets ----
// key = fine5 * NREG + colreg;  Y entry: x = (localrow7<<18)|col18, y = val
__global__ void __launch_bounds__(256)
lgcn_scatter2(const int2* __restrict__ X,
              const int*  __restrict__ cur1,
              int*        __restrict__ cur2,
              int2*       __restrict__ Y) {
    int c  = blockIdx.x / NCH2;
    int ch = blockIdx.x % NCH2;
    int cnt_c = cur1[c]; if (cnt_c > CAPC) cnt_c = CAPC;
    int s = ch * CHUNK;
    int n = cnt_c - s; if (n > CHUNK) n = CHUNK;
    if (n <= 0) return;

    __shared__ int h[NF * NREG];     // 608 counters
    __shared__ int gb[NF * NREG];
    int tid = threadIdx.x;
    size_t base = (size_t)c * CAPC + s;

    for (int j = tid; j < NF * NREG; j += 256) h[j] = 0;
    __syncthreads();
    for (int i = tid; i < n; i += 256) {
        int x = X[base + i].x;
        int key = (x >> 25) * NREG + ((x >> 13) & 31);   // fine5 * 19 + col>>13
        atomicAdd(&h[key], 1);
    }
    __syncthreads();
    for (int j = tid; j < NF * NREG; j += 256) {
        int cc = h[j];
        gb[j] = cc ? atomicAdd(&cur2[c * (NF * NREG) + j], cc) : 0;
        h[j] = 0;
    }
    __syncthreads();
    for (int i = tid; i < n; i += 256) {
        int2 p = X[base + i];
        int key = (p.x >> 25) * NREG + ((p.x >> 13) & 31);
        int rank = atomicAdd(&h[key], 1);
        int o = gb[key] + rank;
        int2 q;
        q.x = p.x & 0x01FFFFFF;      // keep localrow7 (bits 18..24) + col18
        q.y = p.y;
        Y[(o < CAPS) ? ((size_t)(c * (NF * NREG) + key) * CAPS + o)
                     : ((size_t)NSUB * CAPS)] = q;
    }
}

// ---------- init A = bf16(concat(user,item)); init slot table --------------
__global__ void lgcn_init_A(const float* __restrict__ user_emb,
                            const float* __restrict__ item_emb,
                            unsigned short* __restrict__ A,
                            int* __restrict__ slot) {
    int i = blockIdx.x * blockDim.x + threadIdx.x;
    if (i < NELEM) {
        float v = (i < N_USERS * D) ? user_emb[i] : item_emb[i - N_USERS * D];
        __hip_bfloat16 b = __float2bfloat16(v);   // RNE
        A[i] = *(unsigned short*)&b;
    }
    if (i < N_TOTAL) slot[i] = -1;
}

// ---------- record sampled rows: slot_of_row[r] = sample index --------------
// duplicates: last writer wins; every duplicate reads the same surviving slot.
__global__ void lgcn_sampscat(const int* __restrict__ users,
                              const int* __restrict__ items,
                              int* __restrict__ slot) {
    int s = blockIdx.x * blockDim.x + threadIdx.x;
    if (s < BATCH) slot[users[s]] = s;
    else if (s < 2 * BATCH) slot[N_USERS + items[s - BATCH]] = s;
}

// ---------- SpMM: block per 128-row tile, LDS f32 accum, col-region sweep ---
// 4 waves split each region's edge chunks; dual-edge halves; 2 ds_add_f32/lane
// per edge-pair replaces register accum (rows no longer sorted).
__global__ void __launch_bounds__(256)
lgcn_spmm_lds(const int2* __restrict__ Y,
              const int*  __restrict__ cur2,
              const unsigned short* __restrict__ cur,
              unsigned short* __restrict__ nxt) {
    __shared__ __align__(16) float acc[RPB * D];     // 32 KB -> 5 blocks/CU
    const unsigned int* __restrict__ cur32 = (const unsigned int*)cur;
    int fb  = blockIdx.x;
    int tid = threadIdx.x;
    float4* a4 = (float4*)acc;
    #pragma unroll
    for (int i = 0; i < 8; i++) a4[tid + i * 256] = make_float4(0.f, 0.f, 0.f, 0.f);
    __syncthreads();

    int wave = tid >> 6, lane = tid & 63;
    int halfid = lane >> 5, hl = lane & 31;

    for (int reg = 0; reg < NREG; ++reg) {
        int cnt = cur2[fb * NREG + reg]; if (cnt > CAPS) cnt = CAPS;
        const int2* __restrict__ src = Y + (size_t)(fb * NREG + reg) * CAPS;
        for (int b0 = wave * 64; b0 < cnt; b0 += 256) {
            int idx = b0 + lane;
            int2 p = {0, 0};
            if (idx < cnt) p = src[idx];               // coalesced dwordx2
            int m = cnt - b0; if (m > 64) m = 64;
            int jj = 0;
            for (; jj + 8 <= m; jj += 8) {             // 8 edges, unguarded
                #pragma unroll
                for (int k = 0; k < 4; ++k) {
                    int sel = jj + 2 * k + halfid;
                    int   q = __shfl(p.x, sel, 64);
                    float v = __int_as_float(__shfl(p.y, sel, 64));
                    unsigned int u = cur32[(q & 0x3FFFF) * 32 + hl];
                    int lr = q >> 18;                  // <= 127 by encoding
                    atomicAdd(&acc[lr * D + 2 * hl],     v * __uint_as_float(u << 16));
                    atomicAdd(&acc[lr * D + 2 * hl + 1], v * __uint_as_float(u & 0xFFFF0000u));
                }
            }
            if (jj < m) {                              // tail: guarded
                #pragma unroll
                for (int k = 0; k < 4; ++k) {
                    int sel = jj + 2 * k + halfid;
                    int   q = __shfl(p.x, sel, 64);
                    float v = __int_as_float(__shfl(p.y, sel, 64));
                    if (sel >= m) v = 0.f;
                    unsigned int u = cur32[(q & 0x3FFFF) * 32 + hl];
                    int lr = q >> 18;
                    atomicAdd(&acc[lr * D + 2 * hl],     v * __uint_as_float(u << 16));
                    atomicAdd(&acc[lr * D + 2 * hl + 1], v * __uint_as_float(u & 0xFFFF0000u));
                }
            }
        }
    }
    __syncthreads();

    int br = (fb >> 5) * CROWS + (fb & 31) * RPB;
    for (int i = tid; i < RPB * 32; i += 256) {
        int lr = i >> 5, w = i & 31;
        int r = br + lr;
        if (r < N_TOTAL) {
            __hip_bfloat16 a = __float2bfloat16(acc[lr * D + 2 * w]);      // RNE
            __hip_bfloat16 b = __float2bfloat16(acc[lr * D + 2 * w + 1]);
            unsigned int lo = *(unsigned short*)&a;
            unsigned int hi = *(unsigned short*)&b;
            ((unsigned int*)nxt)[r * 32 + w] = lo | (hi << 16);
        }
    }
}

// ---------- layer 3 at sampled rows: per-bucket filtered scan --------------
__global__ void __launch_bounds__(256)
lgcn_spmm_samp(const int2* __restrict__ Y,
               const int*  __restrict__ cur2,
               const unsigned short* __restrict__ cur,
               const int*  __restrict__ slot,
               float* __restrict__ e3) {
    __shared__ __align__(16) float acc[RPB * D];
    __shared__ int rslot[RPB];
    const unsigned int* __restrict__ cur32 = (const unsigned int*)cur;
    int fb = blockIdx.x, tid = threadIdx.x;
    int br = (fb >> 5) * CROWS + (fb & 31) * RPB;
    float4* a4 = (float4*)acc;
    #pragma unroll
    for (int i = 0; i < 8; i++) a4[tid + i * 256] = make_float4(0.f, 0.f, 0.f, 0.f);
    if (tid < RPB) {
        int r = br + tid;
        rslot[tid] = (r < N_TOTAL) ? slot[r] : -1;
    }
    __syncthreads();

    int wave = tid >> 6, lane = tid & 63;
    int halfid = lane >> 5, hl = lane & 31;

    for (int reg = 0; reg < NREG; ++reg) {
        int cnt = cur2[fb * NREG + reg]; if (cnt > CAPS) cnt = CAPS;
        const int2* __restrict__ src = Y + (size_t)(fb * NREG + reg) * CAPS;
        for (int b0 = wave * 64; b0 < cnt; b0 += 256) {
            int idx = b0 + lane;
            int2 p = {0, 0};
            if (idx < cnt) p = src[idx];
            int m = cnt - b0; if (m > 64) m = 64;
            for (int jj = 0; jj < m; jj += 2) {
                int sel = jj + halfid;
                int   q = __shfl(p.x, sel, 64);
                float v = __int_as_float(__shfl(p.y, sel, 64));
                if (sel >= m) v = 0.f;
                int lr = q >> 18;
                int sl = rslot[lr];
                if (sl >= 0 && v != 0.f) {             // ~5.5% of halves gather
                    unsigned int u = cur32[(q & 0x3FFFF) * 32 + hl];
                    atomicAdd(&acc[lr * D + 2 * hl],     v * __uint_as_float(u << 16));
                    atomicAdd(&acc[lr * D + 2 * hl + 1], v * __uint_as_float(u & 0xFFFF0000u));
                }
            }
        }
    }
    __syncthreads();
    for (int i = tid; i < RPB * D; i += 256) {
        int sl = rslot[i >> 6];
        if (sl >= 0) e3[sl * D + (i & 63)] = acc[i];   // f32, one owner per row
    }
}

// ---------- dot: gamma = <E0+E1+E2+E3>_u . <E0+E1+E2+E3>_i / 16 ----------
__global__ void lgcn_dot(const float* __restrict__ user_emb,
                         const float* __restrict__ item_emb,
                         const unsigned short* __restrict__ E1,
                         const unsigned short* __restrict__ E2,
                         const float* __restrict__ e3,
                         const int* __restrict__ slot,
                         const int* __restrict__ users,
                         const int* __restrict__ items,
                         float* __restrict__ out) {
    int t = blockIdx.x * blockDim.x + threadIdx.x;
    int b = t >> 6;
    int d = t & 63;
    if (b < BATCH) {
        int u  = users[b];
        int it = items[b];
        int ur = u * D + d;
        int ir = (N_USERS + it) * D + d;
        int su = slot[u];                 // guaranteed >= 0 (u is sampled)
        int si = slot[N_USERS + it];
        float au = user_emb[ur] + bf2f(E1[ur]) + bf2f(E2[ur]) + e3[su * D + d];
        float ai = item_emb[it * D + d] + bf2f(E1[ir]) + bf2f(E2[ir])
                 + e3[si * D + d];
        float p = au * ai;
        #pragma unroll
        for (int off = 32; off; off >>= 1) p += __shfl_down(p, off, 64);
        if (d == 0) out[b] = p * (1.0f / 16.0f);
    }
}

// ---------- round-1 fallback (atomic scatter) if ws too small ----------
__global__ void lgcn_init_fb(const float* __restrict__ user_emb,
                             const float* __restrict__ item_emb,
                             float* __restrict__ acc,
                             float* __restrict__ cur,
                             float* __restrict__ nxt) {
    int i = blockIdx.x * blockDim.x + threadIdx.x;
    if (i < NELEM) {
        float v = (i < N_USERS * D) ? user_emb[i] : item_emb[i - N_USERS * D];
        acc[i] = v; cur[i] = v; nxt[i] = 0.0f;
    }
}
__global__ void lgcn_spmm_fb(const int* __restrict__ rows,
                             const int* __restrict__ cols,
                             const float* __restrict__ vals,
                             const float* __restrict__ cur,
                             float* __restrict__ nxt) {
    long long t = (long long)blockIdx.x * blockDim.x + threadIdx.x;
    int e = (int)(t >> 6);
    int d = (int)(t & 63);
    if (e < NNZ) {
        float x = cur[cols[e] * D + d];
        unsafeAtomicAdd(&nxt[rows[e] * D + d], vals[e] * x);
    }
}
__global__ void lgcn_accum_fb(float* __restrict__ acc,
                              const float* __restrict__ src,
                              float* __restrict__ to_zero) {
    int i = blockIdx.x * blockDim.x + threadIdx.x;
    if (i < NELEM) {
        acc[i] += src[i];
        if (to_zero) to_zero[i] = 0.0f;
    }
}
__global__ void lgcn_dot_fb(const float* __restrict__ acc,
                            const int* __restrict__ users,
                            const int* __restrict__ items,
                            float* __restrict__ out) {
    int t = blockIdx.x * blockDim.x + threadIdx.x;
    int b = t >> 6;
    int d = t & 63;
    if (b < BATCH) {
        int u  = users[b];
        int it = items[b];
        float p = acc[u * D + d] * acc[(N_USERS + it) * D + d];
        #pragma unroll
        for (int off = 32; off; off >>= 1) p += __shfl_down(p, off, 64);
        if (d == 0) out[b] = p * (1.0f / 16.0f);
    }
}

extern "C" void kernel_launch(void* const* d_in, const int* in_sizes, int n_in,
                              void* d_out, int out_size, void* d_ws, size_t ws_size,
                              hipStream_t stream) {
    const float* user_emb = (const float*)d_in[0];
    const float* item_emb = (const float*)d_in[1];
    const int*   edge_row = (const int*)d_in[2];
    const int*   edge_col = (const int*)d_in[3];
    const float* edge_val = (const float*)d_in[4];
    const int*   users    = (const int*)d_in[5];
    const int*   items    = (const int*)d_in[6];
    float*       out      = (float*)d_out;

    const int TPB = 256;
    int init_blocks = (NELEM + TPB - 1) / TPB;
    int zero_blocks = (NSUB + TPB - 1) / TPB;
    int samp_blocks = (2 * BATCH + TPB - 1) / TPB;
    int dot_blocks  = (BATCH * 64 + TPB - 1) / TPB;

    // workspace layout:
    //   X (coarse pairs, +1 sink)  — dead after pass 2; A,B bf16 + e3 + slot alias it
    //   Y (sub-bucket pairs, +1 sink) — (row-block x col-region) grouped edges
    //   cur1, cur2
    //   C (=E2) aliases A (=E0), which is dead after layer 1.
    int2* X    = (int2*)d_ws;                            // NC*CAPC + 1
    int2* Y    = X + (size_t)NC * CAPC + 1;              // NSUB*CAPS + 1
    int*  cur1 = (int*)(Y + (size_t)NSUB * CAPS + 1);    // NC
    int*  cur2 = cur1 + NC;                              // NSUB
    size_t req = (size_t)((char*)(cur2 + NSUB) - (char*)d_ws);
    unsigned short* A   = (unsigned short*)X;            // E0 (bf16), alias X
    unsigned short* B   = A + NELEM;                     // E1 (bf16)
    float*          e3  = (float*)(B + NELEM);           // 2*BATCH*D f32
    int*            slot = (int*)(e3 + 2 * BATCH * D);   // N_TOTAL
    unsigned short* C   = A;                             // E2 reuses E0 storage

    if (ws_size < req && ws_size >= (size_t)3 * NELEM * 4) {
        // fallback: round-1 atomic path (needs only 3*NELEM floats)
        float* acc = (float*)d_ws;
        float* Af  = acc + NELEM;
        float* Bf  = Af + NELEM;
        long long st = (long long)NNZ * 64;
        int sb = (int)((st + TPB - 1) / TPB);
        lgcn_init_fb<<<init_blocks, TPB, 0, stream>>>(user_emb, item_emb, acc, Af, Bf);
        lgcn_spmm_fb<<<sb, TPB, 0, stream>>>(edge_row, edge_col, edge_val, Af, Bf);
        lgcn_accum_fb<<<init_blocks, TPB, 0, stream>>>(acc, Bf, Af);
        lgcn_spmm_fb<<<sb, TPB, 0, stream>>>(edge_row, edge_col, edge_val, Bf, Af);
        lgcn_accum_fb<<<init_blocks, TPB, 0, stream>>>(acc, Af, Bf);
        lgcn_spmm_fb<<<sb, TPB, 0, stream>>>(edge_row, edge_col, edge_val, Af, Bf);
        lgcn_accum_fb<<<init_blocks, TPB, 0, stream>>>(acc, Bf, nullptr);
        lgcn_dot_fb<<<dot_blocks, TPB, 0, stream>>>(acc, users, items, out);
        return;
    }

    // two-level radix binning into (row-block x col-region); no sort pass
    lgcn_zero<<<zero_blocks, TPB, 0, stream>>>(cur1, cur2);
    lgcn_scatter1<<<EB, TPB, 0, stream>>>(edge_row, edge_col, edge_val, cur1, X);
    lgcn_scatter2<<<NC * NCH2, TPB, 0, stream>>>(X, cur1, cur2, Y);

    // E0 bf16 (A aliases dead X region) + slot table init, then sample scatter
    lgcn_init_A<<<init_blocks, TPB, 0, stream>>>(user_emb, item_emb, A, slot);
    lgcn_sampscat<<<samp_blocks, TPB, 0, stream>>>(users, items, slot);

    // layers 1,2 full width (bf16, LDS-accum, col-region sweep);
    // layer 3 only at sampled rows (f32)
    lgcn_spmm_lds<<<NFB, TPB, 0, stream>>>(Y, cur2, A, B);
    lgcn_spmm_lds<<<NFB, TPB, 0, stream>>>(Y, cur2, B, C);
    lgcn_spmm_samp<<<NFB, TPB, 0, stream>>>(Y, cur2, C, slot, e3);

    // gamma
    lgcn_dot<<<dot_blocks, TPB, 0, stream>>>(user_emb, item_emb, B, C, e3, slot,
                                             users, items, out);
}

// Round 2
// 782.658 us; speedup vs baseline: 7.0506x; 7.0506x over previous
//
#include <hip/hip_runtime.h>
#include <hip/hip_bf16.h>

// LightGCN forward on MI355X — round 11.
// r10 post-mortem: LDS-tile spmm with 1184 blocks was gather-LATENCY-bound
//   (VALU 2.6%, HBM 1.7%, 2393us/layer). The spmm needs ~150k waves; revert
//   to wave-per-row CSR (r9: 107us/layer, VALU 51%, HBM 45%).
// r11: (a) single-pass scatter direct to 1172 row-block buckets (1172 LDS
//   counters fit; two-level radix deleted -> one fewer 102MB pass);
//   (b) oct-edge spmm: 8 lanes/edge, dwordx4 gather (128B row per 8 lanes),
//   2 shfl serve 8 edges -> ~2.6 VALU + 0.125 VMEM issues/edge vs 4.5 + 0.5;
//   tail guards eliminated (v=0 beyond cnt by construction).

#define N_USERS  100000
#define N_ITEMS  50000
#define N_TOTAL  150000          // N_USERS + N_ITEMS
#define D        64
#define NNZ      6400000
#define BATCH    4096
#define NELEM    (N_TOTAL * D)   // 9,600,000
#define CHUNK    8192
#define EB       ((NNZ + CHUNK - 1) / CHUNK)  // 782

#define RPB      128             // rows per bucket
#define NBK      ((N_TOTAL + RPB - 1) / RPB)  // 1172 buckets
#define CAPB     6400            // bucket capacity = mean 5461 + 12.7 sigma

__device__ __forceinline__ float bf2f(unsigned short h) {
    return __uint_as_float(((unsigned int)h) << 16);
}

// ---------- zero cursors ----------
__global__ void lgcn_zero(int* __restrict__ cur) {
    int i = blockIdx.x * blockDim.x + threadIdx.x;
    if (i < NBK) cur[i] = 0;
}

// ---------- single pass: COO -> 1172 row-block buckets, direct scatter ------
// Y pair: x = (localrow7<<18) | col18, y = val bits
__global__ void __launch_bounds__(256)
lgcn_scatter(const int*   __restrict__ rows,
             const int*   __restrict__ cols,
             const float* __restrict__ vals,
             int*         __restrict__ cur,
             int2*        __restrict__ Y) {
    __shared__ int h[NBK];       // 4.7 KB
    __shared__ int gb[NBK];
    int tid = threadIdx.x;
    int s = blockIdx.x * CHUNK;
    int e_end = s + CHUNK; if (e_end > NNZ) e_end = NNZ;

    for (int j = tid; j < NBK; j += 256) h[j] = 0;
    __syncthreads();
    for (int e = s + tid; e < e_end; e += 256)
        atomicAdd(&h[rows[e] >> 7], 1);
    __syncthreads();
    for (int j = tid; j < NBK; j += 256) {
        int c = h[j];
        gb[j] = c ? atomicAdd(&cur[j], c) : 0;
        h[j] = 0;
    }
    __syncthreads();
    for (int e = s + tid; e < e_end; e += 256) {
        int r = rows[e];
        int b = r >> 7;
        int rank = atomicAdd(&h[b], 1);
        int o = gb[b] + rank;
        int2 p;
        p.x = ((r & 127) << 18) | cols[e];
        p.y = __float_as_int(vals[e]);
        Y[(o < CAPB) ? ((size_t)b * CAPB + o) : ((size_t)NBK * CAPB)] = p;
    }
}

// ---------- per-bucket row-exact sort in LDS; emit CSR ----------
__global__ void __launch_bounds__(256)
lgcn_bucket_sort(int2* __restrict__ Y,
                 const int* __restrict__ cur,
                 int* __restrict__ row_ptr,
                 int* __restrict__ row_cnt) {
    __shared__ int2 buf[CAPB];         // 51.2 KB -> 3 blocks/CU
    __shared__ int  h[RPB];
    __shared__ int  base[RPB];
    int tid = threadIdx.x;
    int fb = blockIdx.x;
    size_t start = (size_t)fb * CAPB;
    int cnt = cur[fb]; if (cnt > CAPB) cnt = CAPB;

    for (int i = tid; i < cnt; i += 256) buf[i] = Y[start + i];
    if (tid < RPB) h[tid] = 0;
    __syncthreads();
    for (int i = tid; i < cnt; i += 256) atomicAdd(&h[buf[i].x >> 18], 1);
    __syncthreads();

    // exclusive scan of h[0..127]
    int v = (tid < RPB) ? h[tid] : 0;
    int sum = v;
    #pragma unroll
    for (int off = 1; off < RPB; off <<= 1) {
        if (tid < RPB) base[tid] = sum;
        __syncthreads();
        if (tid >= off && tid < RPB) sum += base[tid - off];
        __syncthreads();
    }
    if (tid < RPB) {
        int excl = sum - v;
        base[tid] = excl;
        int gr = fb * RPB + tid;
        if (gr < N_TOTAL) {
            row_ptr[gr] = (int)start + excl;
            row_cnt[gr] = v;
        }
        h[tid] = 0;                    // reuse as per-row cursor
    }
    __syncthreads();

    for (int i = tid; i < cnt; i += 256) {
        int2 p = buf[i];
        int lr = p.x >> 18;
        int rank = atomicAdd(&h[lr], 1);
        Y[start + base[lr] + rank] = p;   // in place; window 51KB -> L2
    }
}

// ---------- init A = bf16(concat(user,item)) ----------
__global__ void lgcn_init_A(const float* __restrict__ user_emb,
                            const float* __restrict__ item_emb,
                            unsigned short* __restrict__ A) {
    int i = blockIdx.x * blockDim.x + threadIdx.x;
    if (i < NELEM) {
        float v = (i < N_USERS * D) ? user_emb[i] : item_emb[i - N_USERS * D];
        __hip_bfloat16 b = __float2bfloat16(v);   // RNE
        A[i] = *(unsigned short*)&b;
    }
}

// ---------- SpMM: wave per row, oct-edge (8 edges per shfl pair) ----------
// lane = 8*q + h8; slot q processes edge (jj+8k+q); lane loads dwordx4
// (dims 8*h8 .. 8*h8+7). 8 lanes x 16B cover the 128B row. Out-of-range
// slots carry v=0 naturally (p={0,0} beyond cnt). 3-round shfl_xor reduce.
__global__ void __launch_bounds__(256)
lgcn_spmm_csr(const int2* __restrict__ pairs,
              const int*  __restrict__ row_ptr,
              const int*  __restrict__ row_cnt,
              const unsigned short* __restrict__ cur,
              unsigned short* __restrict__ nxt) {
    int t = blockIdx.x * blockDim.x + threadIdx.x;
    int r = t >> 6;
    int lane = t & 63;
    if (r >= N_TOTAL) return;
    int q  = lane >> 3;          // edge slot 0..7
    int h8 = lane & 7;           // dim block: dims 8*h8 .. 8*h8+7
    const uint4* __restrict__ curq = (const uint4*)cur + h8;   // lane-hoisted
    int start = row_ptr[r];
    int cnt   = row_cnt[r];
    float s0=0.f, s1=0.f, s2=0.f, s3=0.f, s4=0.f, s5=0.f, s6=0.f, s7=0.f;
    for (int b0 = 0; b0 < cnt; b0 += 64) {
        int idx = b0 + lane;
        int2 p = {0, 0};
        if (idx < cnt) p = pairs[start + idx];     // coalesced dwordx2
        int m = cnt - b0; if (m > 64) m = 64;
        for (int jj = 0; jj < m; jj += 16) {       // no tail guard needed
            #pragma unroll
            for (int k = 0; k < 2; ++k) {
                int sel = jj + 8 * k + q;          // <= 63 always
                int   c = __shfl(p.x, sel, 64);
                float v = __int_as_float(__shfl(p.y, sel, 64));
                uint4 u = curq[(size_t)(c & 0x3FFFF) * 8];
                s0 = fmaf(v, __uint_as_float(u.x << 16),          s0);
                s1 = fmaf(v, __uint_as_float(u.x & 0xFFFF0000u),  s1);
                s2 = fmaf(v, __uint_as_float(u.y << 16),          s2);
                s3 = fmaf(v, __uint_as_float(u.y & 0xFFFF0000u),  s3);
                s4 = fmaf(v, __uint_as_float(u.z << 16),          s4);
                s5 = fmaf(v, __uint_as_float(u.z & 0xFFFF0000u),  s5);
                s6 = fmaf(v, __uint_as_float(u.w << 16),          s6);
                s7 = fmaf(v, __uint_as_float(u.w & 0xFFFF0000u),  s7);
            }
        }
    }
    // combine the 8 edge slots (lanes sharing h8)
    #pragma unroll
    for (int off = 8; off < 64; off <<= 1) {
        s0 += __shfl_xor(s0, off, 64); s1 += __shfl_xor(s1, off, 64);
        s2 += __shfl_xor(s2, off, 64); s3 += __shfl_xor(s3, off, 64);
        s4 += __shfl_xor(s4, off, 64); s5 += __shfl_xor(s5, off, 64);
        s6 += __shfl_xor(s6, off, 64); s7 += __shfl_xor(s7, off, 64);
    }
    if (q == 0) {
        __hip_bfloat16 b0 = __float2bfloat16(s0), b1 = __float2bfloat16(s1);
        __hip_bfloat16 b2 = __float2bfloat16(s2), b3 = __float2bfloat16(s3);
        __hip_bfloat16 b4 = __float2bfloat16(s4), b5 = __float2bfloat16(s5);
        __hip_bfloat16 b6 = __float2bfloat16(s6), b7 = __float2bfloat16(s7);
        uint4 w;
        w.x = *(unsigned short*)&b0 | ((unsigned int)*(unsigned short*)&b1 << 16);
        w.y = *(unsigned short*)&b2 | ((unsigned int)*(unsigned short*)&b3 << 16);
        w.z = *(unsigned short*)&b4 | ((unsigned int)*(unsigned short*)&b5 << 16);
        w.w = *(unsigned short*)&b6 | ((unsigned int)*(unsigned short*)&b7 << 16);
        ((uint4*)nxt)[r * 8 + h8] = w;             // 8 lanes x 16B = 128B
    }
}

// ---------- layer 3 at sampled rows only (f32 out), oct-edge ----------
__global__ void __launch_bounds__(256)
lgcn_spmm_sampled(const int2* __restrict__ pairs,
                  const int*  __restrict__ row_ptr,
                  const int*  __restrict__ row_cnt,
                  const unsigned short* __restrict__ cur,
                  const int* __restrict__ users,
                  const int* __restrict__ items,
                  float* __restrict__ e3) {
    int t = blockIdx.x * blockDim.x + threadIdx.x;
    int s = t >> 6;
    int lane = t & 63;
    if (s >= 2 * BATCH) return;
    int r = (s < BATCH) ? users[s] : (N_USERS + items[s - BATCH]);
    int q  = lane >> 3;
    int h8 = lane & 7;
    const uint4* __restrict__ curq = (const uint4*)cur + h8;
    int start = row_ptr[r];
    int cnt   = row_cnt[r];
    float s0=0.f, s1=0.f, s2=0.f, s3=0.f, s4=0.f, s5=0.f, s6=0.f, s7=0.f;
    for (int b0 = 0; b0 < cnt; b0 += 64) {
        int idx = b0 + lane;
        int2 p = {0, 0};
        if (idx < cnt) p = pairs[start + idx];
        int m = cnt - b0; if (m > 64) m = 64;
        for (int jj = 0; jj < m; jj += 16) {
            #pragma unroll
            for (int k = 0; k < 2; ++k) {
                int sel = jj + 8 * k + q;
                int   c = __shfl(p.x, sel, 64);
                float v = __int_as_float(__shfl(p.y, sel, 64));
                uint4 u = curq[(size_t)(c & 0x3FFFF) * 8];
                s0 = fmaf(v, __uint_as_float(u.x << 16),          s0);
                s1 = fmaf(v, __uint_as_float(u.x & 0xFFFF0000u),  s1);
                s2 = fmaf(v, __uint_as_float(u.y << 16),          s2);
                s3 = fmaf(v, __uint_as_float(u.y & 0xFFFF0000u),  s3);
                s4 = fmaf(v, __uint_as_float(u.z << 16),          s4);
                s5 = fmaf(v, __uint_as_float(u.z & 0xFFFF0000u),  s5);
                s6 = fmaf(v, __uint_as_float(u.w << 16),          s6);
                s7 = fmaf(v, __uint_as_float(u.w & 0xFFFF0000u),  s7);
            }
        }
    }
    #pragma unroll
    for (int off = 8; off < 64; off <<= 1) {
        s0 += __shfl_xor(s0, off, 64); s1 += __shfl_xor(s1, off, 64);
        s2 += __shfl_xor(s2, off, 64); s3 += __shfl_xor(s3, off, 64);
        s4 += __shfl_xor(s4, off, 64); s5 += __shfl_xor(s5, off, 64);
        s6 += __shfl_xor(s6, off, 64); s7 += __shfl_xor(s7, off, 64);
    }
    if (q == 0) {
        float4 wa = make_float4(s0, s1, s2, s3);
        float4 wb = make_float4(s4, s5, s6, s7);
        ((float4*)e3)[s * 16 + 2 * h8]     = wa;
        ((float4*)e3)[s * 16 + 2 * h8 + 1] = wb;
    }
}

// ---------- dot: gamma = <E0+E1+E2+E3>_u . <E0+E1+E2+E3>_i / 16 ----------
__global__ void lgcn_dot(const float* __restrict__ user_emb,
                         const float* __restrict__ item_emb,
                         const unsigned short* __restrict__ E1,
                         const unsigned short* __restrict__ E2,
                         const float* __restrict__ e3,
                         const int* __restrict__ users,
                         const int* __restrict__ items,
                         float* __restrict__ out) {
    int t = blockIdx.x * blockDim.x + threadIdx.x;
    int b = t >> 6;
    int d = t & 63;
    if (b < BATCH) {
        int u  = users[b];
        int it = items[b];
        int ur = u * D + d;
        int ir = (N_USERS + it) * D + d;
        float au = user_emb[ur] + bf2f(E1[ur]) + bf2f(E2[ur]) + e3[b * D + d];
        float ai = item_emb[it * D + d] + bf2f(E1[ir]) + bf2f(E2[ir])
                 + e3[(BATCH + b) * D + d];
        float p = au * ai;
        #pragma unroll
        for (int off = 32; off; off >>= 1) p += __shfl_down(p, off, 64);
        if (d == 0) out[b] = p * (1.0f / 16.0f);
    }
}

// ---------- round-1 fallback (atomic scatter) if ws too small ----------
__global__ void lgcn_init_fb(const float* __restrict__ user_emb,
                             const float* __restrict__ item_emb,
                             float* __restrict__ acc,
                             float* __restrict__ cur,
                             float* __restrict__ nxt) {
    int i = blockIdx.x * blockDim.x + threadIdx.x;
    if (i < NELEM) {
        float v = (i < N_USERS * D) ? user_emb[i] : item_emb[i - N_USERS * D];
        acc[i] = v; cur[i] = v; nxt[i] = 0.0f;
    }
}
__global__ void lgcn_spmm_fb(const int* __restrict__ rows,
                             const int* __restrict__ cols,
                             const float* __restrict__ vals,
                             const float* __restrict__ cur,
                             float* __restrict__ nxt) {
    long long t = (long long)blockIdx.x * blockDim.x + threadIdx.x;
    int e = (int)(t >> 6);
    int d = (int)(t & 63);
    if (e < NNZ) {
        float x = cur[cols[e] * D + d];
        unsafeAtomicAdd(&nxt[rows[e] * D + d], vals[e] * x);
    }
}
__global__ void lgcn_accum_fb(float* __restrict__ acc,
                              const float* __restrict__ src,
                              float* __restrict__ to_zero) {
    int i = blockIdx.x * blockDim.x + threadIdx.x;
    if (i < NELEM) {
        acc[i] += src[i];
        if (to_zero) to_zero[i] = 0.0f;
    }
}
__global__ void lgcn_dot_fb(const float* __restrict__ acc,
                            const int* __restrict__ users,
                            const int* __restrict__ items,
                            float* __restrict__ out) {
    int t = blockIdx.x * blockDim.x + threadIdx.x;
    int b = t >> 6;
    int d = t & 63;
    if (b < BATCH) {
        int u  = users[b];
        int it = items[b];
        float p = acc[u * D + d] * acc[(N_USERS + it) * D + d];
        #pragma unroll
        for (int off = 32; off; off >>= 1) p += __shfl_down(p, off, 64);
        if (d == 0) out[b] = p * (1.0f / 16.0f);
    }
}

extern "C" void kernel_launch(void* const* d_in, const int* in_sizes, int n_in,
                              void* d_out, int out_size, void* d_ws, size_t ws_size,
                              hipStream_t stream) {
    const float* user_emb = (const float*)d_in[0];
    const float* item_emb = (const float*)d_in[1];
    const int*   edge_row = (const int*)d_in[2];
    const int*   edge_col = (const int*)d_in[3];
    const float* edge_val = (const float*)d_in[4];
    const int*   users    = (const int*)d_in[5];
    const int*   items    = (const int*)d_in[6];
    float*       out      = (float*)d_out;

    const int TPB = 256;
    int init_blocks = (NELEM + TPB - 1) / TPB;
    int zero_blocks = (NBK + TPB - 1) / TPB;
    int spmm_blocks = (N_TOTAL * 64 + TPB - 1) / TPB;       // wave per row
    int samp_blocks = (2 * BATCH * 64 + TPB - 1) / TPB;     // wave per sampled row
    int dot_blocks  = (BATCH * 64 + TPB - 1) / TPB;

    // workspace layout (no aliasing needed; req ~121MB < r9's 137MB):
    //   Y (bucket pairs, +2 sink/align) — sorted in place to CSR
    //   A, B, C bf16 tables; e3 f32; cur; row_ptr; row_cnt
    int2* Y = (int2*)d_ws;                               // NBK*CAPB + 2
    unsigned short* A = (unsigned short*)(Y + (size_t)NBK * CAPB + 2);  // NELEM
    unsigned short* B = A + NELEM;                       // NELEM
    unsigned short* C = B + NELEM;                       // NELEM
    float* e3 = (float*)(C + NELEM);                     // 2*BATCH*D
    int* cur = (int*)(e3 + 2 * BATCH * D);               // NBK
    int* row_ptr = cur + NBK;                            // NBK*RPB
    int* row_cnt = row_ptr + NBK * RPB;                  // NBK*RPB
    size_t req = (size_t)((char*)(row_cnt + NBK * RPB) - (char*)d_ws);

    if (ws_size < req && ws_size >= (size_t)3 * NELEM * 4) {
        // fallback: round-1 atomic path (needs only 3*NELEM floats)
        float* acc = (float*)d_ws;
        float* Af  = acc + NELEM;
        float* Bf  = Af + NELEM;
        long long st = (long long)NNZ * 64;
        int sb = (int)((st + TPB - 1) / TPB);
        lgcn_init_fb<<<init_blocks, TPB, 0, stream>>>(user_emb, item_emb, acc, Af, Bf);
        lgcn_spmm_fb<<<sb, TPB, 0, stream>>>(edge_row, edge_col, edge_val, Af, Bf);
        lgcn_accum_fb<<<init_blocks, TPB, 0, stream>>>(acc, Bf, Af);
        lgcn_spmm_fb<<<sb, TPB, 0, stream>>>(edge_row, edge_col, edge_val, Bf, Af);
        lgcn_accum_fb<<<init_blocks, TPB, 0, stream>>>(acc, Af, Bf);
        lgcn_spmm_fb<<<sb, TPB, 0, stream>>>(edge_row, edge_col, edge_val, Af, Bf);
        lgcn_accum_fb<<<init_blocks, TPB, 0, stream>>>(acc, Bf, nullptr);
        lgcn_dot_fb<<<dot_blocks, TPB, 0, stream>>>(acc, users, items, out);
        return;
    }

    // single-pass radix binning + in-place row sort
    lgcn_zero<<<zero_blocks, TPB, 0, stream>>>(cur);
    lgcn_scatter<<<EB, TPB, 0, stream>>>(edge_row, edge_col, edge_val, cur, Y);
    lgcn_bucket_sort<<<NBK, TPB, 0, stream>>>(Y, cur, row_ptr, row_cnt);

    // E0 bf16
    lgcn_init_A<<<init_blocks, TPB, 0, stream>>>(user_emb, item_emb, A);

    // layers 1,2 full width (bf16); layer 3 only at sampled rows (f32)
    lgcn_spmm_csr<<<spmm_blocks, TPB, 0, stream>>>(Y, row_ptr, row_cnt, A, B);
    lgcn_spmm_csr<<<spmm_blocks, TPB, 0, stream>>>(Y, row_ptr, row_cnt, B, C);
    lgcn_spmm_sampled<<<samp_blocks, TPB, 0, stream>>>(Y, row_ptr, row_cnt, C,
                                                       users, items, e3);

    // gamma
    lgcn_dot<<<dot_blocks, TPB, 0, stream>>>(user_emb, item_emb, B, C, e3,
                                             users, items, out);
}

// Round 4
// 762.579 us; speedup vs baseline: 7.2362x; 1.0263x over previous
//
#include <hip/hip_runtime.h>
#include <hip/hip_bf16.h>

// LightGCN forward on MI355X — round 13 (= r12 resubmit; r3 bench was an
//   infra failure "container failed twice", no profile/verdict produced).
// r10 post-mortem: LDS-tile spmm (1184 blocks) gather-latency-bound — spmm
//   needs ~150k waves (wave-per-row).
// r11 post-mortem: single-pass 1172-way scatter = 228us (WRITE 196MB, 4x amp,
//   8B random stores over 60MB span). Two-level radix restored. Oct-edge spmm
//   unproven vs dual-edge (budget says worse) -> dual-edge restored verbatim.
// r12/r13: r9 pipeline (526us proven) + (a) bucket_sort RPB 128->64 (27.6KB
//   LDS, 3->5 blocks/CU, 12->20 waves/CU latency hiding); (b) A,B,C all alias
//   dead X (CAPC 194600 so X >= 57.6MB); req ~126MB; (c) nontemporal hints on
//   stream-once pair traffic (gather table keeps L2).

#define N_USERS  100000
#define N_ITEMS  50000
#define N_TOTAL  150000          // N_USERS + N_ITEMS
#define D        64
#define NNZ      6400000
#define BATCH    4096
#define NELEM    (N_TOTAL * D)   // 9,600,000
#define CHUNK    8192
#define EB       ((NNZ + CHUNK - 1) / CHUNK)  // 782

#define NC       37              // coarse buckets (4096 rows each)
#define CROWS    4096
#define CAPC     194600          // coarse capacity (mean 174763 + 48 sigma);
                                 // also sized so X >= A+B+C (57.6MB aliasing)
#define NCH2     ((CAPC + CHUNK - 1) / CHUNK)  // 24 chunks per coarse region
#define NF       64              // fine buckets per coarse (64 rows each)
#define RPB      64
#define NBUK     (NC * NF)       // 2368 fine buckets
#define CAPF     3456            // fine capacity = mean 2703 + 14 sigma

__device__ __forceinline__ float bf2f(unsigned short h) {
    return __uint_as_float(((unsigned int)h) << 16);
}
__device__ __forceinline__ int2 ntload_i2(const int2* p) {
    long long v = __builtin_nontemporal_load((const long long*)p);
    int2 r; r.x = (int)(unsigned int)(v & 0xFFFFFFFFLL); r.y = (int)(v >> 32);
    return r;
}
__device__ __forceinline__ void ntstore_i2(int2* p, int2 q) {
    long long v = (long long)(unsigned int)q.x | ((long long)q.y << 32);
    __builtin_nontemporal_store(v, (long long*)p);
}

// ---------- zero cursors ----------
__global__ void lgcn_zero(int* __restrict__ cur1, int* __restrict__ cur2) {
    int i = threadIdx.x;
    if (i < NC) cur1[i] = 0;
    for (int j = i; j < NBUK; j += 256) cur2[j] = 0;
}

// ---------- pass 1: COO -> 37 coarse buckets, direct scatter ----------
// X pair: x = (row_in_coarse<<18) | col  (12b + 18b), y = val bits
__global__ void __launch_bounds__(256)
lgcn_scatter1(const int*   __restrict__ rows,
              const int*   __restrict__ cols,
              const float* __restrict__ vals,
              int*         __restrict__ cur1,
              int2*        __restrict__ X) {
    __shared__ int h[NC];
    __shared__ int gb[NC];
    int tid = threadIdx.x;
    int s = blockIdx.x * CHUNK;
    int e_end = s + CHUNK; if (e_end > NNZ) e_end = NNZ;

    if (tid < NC) h[tid] = 0;
    __syncthreads();
    for (int e = s + tid; e < e_end; e += 256)
        atomicAdd(&h[__builtin_nontemporal_load(&rows[e]) >> 12], 1);
    __syncthreads();
    if (tid < NC) {
        int c = h[tid];
        gb[tid] = c ? atomicAdd(&cur1[tid], c) : 0;
        h[tid] = 0;
    }
    __syncthreads();
    for (int e = s + tid; e < e_end; e += 256) {
        int r = __builtin_nontemporal_load(&rows[e]);
        int c = r >> 12;
        int rank = atomicAdd(&h[c], 1);
        int o = gb[c] + rank;
        int2 p;
        p.x = ((r & 4095) << 18) | __builtin_nontemporal_load(&cols[e]);
        p.y = __float_as_int(__builtin_nontemporal_load(&vals[e]));
        ntstore_i2(&X[(o < CAPC) ? ((size_t)c * CAPC + o) : ((size_t)NC * CAPC)], p);
    }
}

// ---------- pass 2: coarse region -> 64 fine buckets, direct scatter ----------
__global__ void __launch_bounds__(256)
lgcn_scatter2(const int2* __restrict__ X,
              const int*  __restrict__ cur1,
              int*        __restrict__ cur2,
              int2*       __restrict__ Y) {
    int c = blockIdx.x / NCH2;
    int ch = blockIdx.x % NCH2;
    int cnt_c = cur1[c]; if (cnt_c > CAPC) cnt_c = CAPC;
    int s = ch * CHUNK;
    int n = cnt_c - s; if (n > CHUNK) n = CHUNK;
    if (n <= 0) return;                       // uniform per block

    __shared__ int h[NF];
    __shared__ int gb[NF];
    int tid = threadIdx.x;
    size_t base = (size_t)c * CAPC + s;

    if (tid < NF) h[tid] = 0;
    __syncthreads();
    for (int i = tid; i < n; i += 256)
        atomicAdd(&h[__builtin_nontemporal_load(&X[base + i].x) >> 24], 1);
    __syncthreads();
    if (tid < NF) {
        int cc = h[tid];
        gb[tid] = cc ? atomicAdd(&cur2[c * NF + tid], cc) : 0;
        h[tid] = 0;
    }
    __syncthreads();
    for (int i = tid; i < n; i += 256) {
        int2 p = ntload_i2(&X[base + i]);
        int f = p.x >> 24;                    // fine6 = lr12 >> 6
        int rank = atomicAdd(&h[f], 1);
        int o = gb[f] + rank;
        int2 q;
        q.x = p.x & 0x00FFFFFF;               // keep lr6 (bits 18..23) + col18
        q.y = p.y;
        ntstore_i2(&Y[(o < CAPF) ? ((size_t)(c * NF + f) * CAPF + o)
                                 : ((size_t)NBUK * CAPF)], q);
    }
}

// ---------- pass 3: in-place per-fine-bucket row-exact sort; emit CSR ----------
__global__ void __launch_bounds__(256)
lgcn_bucket_sort(int2* __restrict__ Y,
                 const int* __restrict__ cur2,
                 int* __restrict__ row_ptr,
                 int* __restrict__ row_cnt) {
    __shared__ int2 buf[CAPF];         // 27.6 KB -> 5 blocks/CU
    __shared__ int  h[RPB];
    __shared__ int  base[RPB];
    int tid = threadIdx.x;
    int fb = blockIdx.x;
    size_t start = (size_t)fb * CAPF;
    int cnt = cur2[fb]; if (cnt > CAPF) cnt = CAPF;

    for (int i = tid; i < cnt; i += 256) buf[i] = ntload_i2(&Y[start + i]);
    if (tid < RPB) h[tid] = 0;
    __syncthreads();
    for (int i = tid; i < cnt; i += 256) atomicAdd(&h[buf[i].x >> 18], 1);
    __syncthreads();

    // exclusive scan of h[0..63]
    int v = (tid < RPB) ? h[tid] : 0;
    int sum = v;
    #pragma unroll
    for (int off = 1; off < RPB; off <<= 1) {
        if (tid < RPB) base[tid] = sum;
        __syncthreads();
        if (tid >= off && tid < RPB) sum += base[tid - off];
        __syncthreads();
    }
    if (tid < RPB) {
        int excl = sum - v;
        base[tid] = excl;
        int gr = (fb >> 6) * CROWS + (fb & 63) * RPB + tid;
        if (gr < N_TOTAL) {
            row_ptr[gr] = (int)start + excl;
            row_cnt[gr] = v;
        }
        h[tid] = 0;                    // reuse as per-row cursor
    }
    __syncthreads();

    for (int i = tid; i < cnt; i += 256) {
        int2 p = buf[i];
        int lr = p.x >> 18;
        int rank = atomicAdd(&h[lr], 1);
        Y[start + base[lr] + rank] = p;   // in place; 27KB window -> L2
    }
}

// ---------- init A = bf16(concat(user,item)) (after pass 2: A aliases X) ------
__global__ void lgcn_init_A(const float* __restrict__ user_emb,
                            const float* __restrict__ item_emb,
                            unsigned short* __restrict__ A) {
    int i = blockIdx.x * blockDim.x + threadIdx.x;
    if (i < NELEM) {
        float v = (i < N_USERS * D)
                ? __builtin_nontemporal_load(&user_emb[i])
                : __builtin_nontemporal_load(&item_emb[i - N_USERS * D]);
        __hip_bfloat16 b = __float2bfloat16(v);   // RNE
        A[i] = *(unsigned short*)&b;
    }
}

// ---------- SpMM: wave per row, dual-edge (2 edges per wave-iter) ----------
// lane = 32*half + hl; half h processes edge (jj+2k+h); lane loads a dword
// (dims 2hl, 2hl+1). Cross-half combine via shfl_xor(32); packed uint stores.
__global__ void lgcn_spmm_csr(const int2* __restrict__ pairs,
                              const int*  __restrict__ row_ptr,
                              const int*  __restrict__ row_cnt,
                              const unsigned short* __restrict__ cur,
                              unsigned short* __restrict__ nxt) {
    const unsigned int* __restrict__ cur32 = (const unsigned int*)cur;
    int t = blockIdx.x * blockDim.x + threadIdx.x;
    int r = t >> 6;
    int lane = t & 63;
    if (r >= N_TOTAL) return;
    int halfid = lane >> 5;
    int hl = lane & 31;
    int start = row_ptr[r];
    int cnt   = row_cnt[r];
    float sA = 0.f, sB = 0.f;
    for (int base = 0; base < cnt; base += 64) {
        int idx = base + lane;
        int2 p = {0, 0};
        if (idx < cnt) p = ntload_i2(&pairs[start + idx]);   // coalesced dwordx2
        int m = cnt - base; if (m > 64) m = 64;
        int jj = 0;
        for (; jj + 8 <= m; jj += 8) {             // 8 edges, unguarded
            #pragma unroll
            for (int k = 0; k < 4; k++) {
                int sel = jj + 2 * k + halfid;
                int   c = __shfl(p.x, sel, 64);
                float v = __int_as_float(__shfl(p.y, sel, 64));
                unsigned int u = cur32[(c & 0x3FFFF) * 32 + hl];
                sA = fmaf(v, __uint_as_float(u << 16), sA);
                sB = fmaf(v, __uint_as_float(u & 0xFFFF0000u), sB);
            }
        }
        if (jj < m) {                              // tail: guarded (p=0 beyond cnt)
            #pragma unroll
            for (int k = 0; k < 4; k++) {
                int sel = jj + 2 * k + halfid;
                int   c = __shfl(p.x, sel, 64);
                float v = __int_as_float(__shfl(p.y, sel, 64));
                if (sel >= m) v = 0.f;
                unsigned int u = cur32[(c & 0x3FFFF) * 32 + hl];
                sA = fmaf(v, __uint_as_float(u << 16), sA);
                sB = fmaf(v, __uint_as_float(u & 0xFFFF0000u), sB);
            }
        }
    }
    sA += __shfl_xor(sA, 32, 64);
    sB += __shfl_xor(sB, 32, 64);
    if (halfid == 0) {
        __hip_bfloat16 a = __float2bfloat16(sA);   // RNE
        __hip_bfloat16 b = __float2bfloat16(sB);
        unsigned int lo = *(unsigned short*)&a;
        unsigned int hi = *(unsigned short*)&b;
        ((unsigned int*)nxt)[r * 32 + hl] = lo | (hi << 16);  // half-wave 128B
    }
}

// ---------- layer 3 at sampled rows only: e3[s,:] = (A @ E2)[row(s),:] (f32) ----
__global__ void lgcn_spmm_sampled(const int2* __restrict__ pairs,
                                  const int*  __restrict__ row_ptr,
                                  const int*  __restrict__ row_cnt,
                                  const unsigned short* __restrict__ cur,
                                  const int* __restrict__ users,
                                  const int* __restrict__ items,
                                  float* __restrict__ e3) {
    int t = blockIdx.x * blockDim.x + threadIdx.x;
    int s = t >> 6;
    int lane = t & 63;
    if (s >= 2 * BATCH) return;
    int r = (s < BATCH) ? users[s] : (N_USERS + items[s - BATCH]);
    int start = row_ptr[r];
    int cnt   = row_cnt[r];
    float sum0 = 0.f, sum1 = 0.f;
    for (int base = 0; base < cnt; base += 64) {
        int idx = base + lane;
        int2 p = {0, 0};
        if (idx < cnt) p = ntload_i2(&pairs[start + idx]);
        int m = cnt - base; if (m > 64) m = 64;
        int j = 0;
        for (; j + 8 <= m; j += 8) {
            float acc[8];
            #pragma unroll
            for (int k = 0; k < 8; k++) {
                int   c = __shfl(p.x, j + k, 64);
                float v = __int_as_float(__shfl(p.y, j + k, 64));
                acc[k] = v * bf2f(cur[(c & 0x3FFFF) * D + lane]);
            }
            sum0 += acc[0] + acc[2] + acc[4] + acc[6];
            sum1 += acc[1] + acc[3] + acc[5] + acc[7];
        }
        for (; j < m; j++) {
            int   c = __shfl(p.x, j, 64);
            float v = __int_as_float(__shfl(p.y, j, 64));
            sum0 += v * bf2f(cur[(c & 0x3FFFF) * D + lane]);
        }
    }
    e3[s * D + lane] = sum0 + sum1;
}

// ---------- dot: gamma = <E0+E1+E2+E3>_u . <E0+E1+E2+E3>_i / 16 ----------
__global__ void lgcn_dot(const float* __restrict__ user_emb,
                         const float* __restrict__ item_emb,
                         const unsigned short* __restrict__ E1,
                         const unsigned short* __restrict__ E2,
                         const float* __restrict__ e3,
                         const int* __restrict__ users,
                         const int* __restrict__ items,
                         float* __restrict__ out) {
    int t = blockIdx.x * blockDim.x + threadIdx.x;
    int b = t >> 6;
    int d = t & 63;
    if (b < BATCH) {
        int u  = users[b];
        int it = items[b];
        int ur = u * D + d;
        int ir = (N_USERS + it) * D + d;
        float au = user_emb[ur] + bf2f(E1[ur]) + bf2f(E2[ur]) + e3[b * D + d];
        float ai = item_emb[it * D + d] + bf2f(E1[ir]) + bf2f(E2[ir])
                 + e3[(BATCH + b) * D + d];
        float p = au * ai;
        #pragma unroll
        for (int off = 32; off; off >>= 1) p += __shfl_down(p, off, 64);
        if (d == 0) out[b] = p * (1.0f / 16.0f);
    }
}

// ---------- round-1 fallback (atomic scatter) if ws too small ----------
__global__ void lgcn_init_fb(const float* __restrict__ user_emb,
                             const float* __restrict__ item_emb,
                             float* __restrict__ acc,
                             float* __restrict__ cur,
                             float* __restrict__ nxt) {
    int i = blockIdx.x * blockDim.x + threadIdx.x;
    if (i < NELEM) {
        float v = (i < N_USERS * D) ? user_emb[i] : item_emb[i - N_USERS * D];
        acc[i] = v; cur[i] = v; nxt[i] = 0.0f;
    }
}
__global__ void lgcn_spmm_fb(const int* __restrict__ rows,
                             const int* __restrict__ cols,
                             const float* __restrict__ vals,
                             const float* __restrict__ cur,
                             float* __restrict__ nxt) {
    long long t = (long long)blockIdx.x * blockDim.x + threadIdx.x;
    int e = (int)(t >> 6);
    int d = (int)(t & 63);
    if (e < NNZ) {
        float x = cur[cols[e] * D + d];
        unsafeAtomicAdd(&nxt[rows[e] * D + d], vals[e] * x);
    }
}
__global__ void lgcn_accum_fb(float* __restrict__ acc,
                              const float* __restrict__ src,
                              float* __restrict__ to_zero) {
    int i = blockIdx.x * blockDim.x + threadIdx.x;
    if (i < NELEM) {
        acc[i] += src[i];
        if (to_zero) to_zero[i] = 0.0f;
    }
}
__global__ void lgcn_dot_fb(const float* __restrict__ acc,
                            const int* __restrict__ users,
                            const int* __restrict__ items,
                            float* __restrict__ out) {
    int t = blockIdx.x * blockDim.x + threadIdx.x;
    int b = t >> 6;
    int d = t & 63;
    if (b < BATCH) {
        int u  = users[b];
        int it = items[b];
        float p = acc[u * D + d] * acc[(N_USERS + it) * D + d];
        #pragma unroll
        for (int off = 32; off; off >>= 1) p += __shfl_down(p, off, 64);
        if (d == 0) out[b] = p * (1.0f / 16.0f);
    }
}

extern "C" void kernel_launch(void* const* d_in, const int* in_sizes, int n_in,
                              void* d_out, int out_size, void* d_ws, size_t ws_size,
                              hipStream_t stream) {
    const float* user_emb = (const float*)d_in[0];
    const float* item_emb = (const float*)d_in[1];
    const int*   edge_row = (const int*)d_in[2];
    const int*   edge_col = (const int*)d_in[3];
    const float* edge_val = (const float*)d_in[4];
    const int*   users    = (const int*)d_in[5];
    const int*   items    = (const int*)d_in[6];
    float*       out      = (float*)d_out;

    const int TPB = 256;
    int init_blocks = (NELEM + TPB - 1) / TPB;
    int spmm_blocks = (N_TOTAL * 64 + TPB - 1) / TPB;       // wave per row
    int samp_blocks = (2 * BATCH * 64 + TPB - 1) / TPB;     // wave per sampled row
    int dot_blocks  = (BATCH * 64 + TPB - 1) / TPB;

    // workspace layout (~126.4MB):
    //   X (coarse pairs, +1 sink) — dead after pass 2; A,B,C bf16 ALL alias it
    //     (CAPC sized so X bytes >= 3*NELEM*2 = 57.6MB)
    //   Y (fine pairs, +1 sink)   — final row-sorted CSR pairs (in-place sort)
    //   e3 f32, cursors, row_ptr/row_cnt
    int2* X = (int2*)d_ws;                              // NC*CAPC + 1
    int2* Y = X + (size_t)NC * CAPC + 1;                // NBUK*CAPF + 1
    float* e3 = (float*)(Y + (size_t)NBUK * CAPF + 1);  // 2*BATCH*D
    int* cur1 = (int*)(e3 + 2 * BATCH * D);             // NC
    int* cur2 = cur1 + NC;                              // NBUK
    int* row_ptr = cur2 + NBUK;                         // NBUK*RPB
    int* row_cnt = row_ptr + NBUK * RPB;                // NBUK*RPB
    size_t req = (size_t)((char*)(row_cnt + NBUK * RPB) - (char*)d_ws);
    unsigned short* A = (unsigned short*)X;             // alias: init after pass 2
    unsigned short* B = A + NELEM;                      // alias
    unsigned short* C = B + NELEM;                      // alias: 57.6MB <= X bytes

    if (ws_size < req && ws_size >= (size_t)3 * NELEM * 4) {
        // fallback: round-1 atomic path (needs only 3*NELEM floats)
        float* acc = (float*)d_ws;
        float* Af  = acc + NELEM;
        float* Bf  = Af + NELEM;
        long long st = (long long)NNZ * 64;
        int sb = (int)((st + TPB - 1) / TPB);
        lgcn_init_fb<<<init_blocks, TPB, 0, stream>>>(user_emb, item_emb, acc, Af, Bf);
        lgcn_spmm_fb<<<sb, TPB, 0, stream>>>(edge_row, edge_col, edge_val, Af, Bf);
        lgcn_accum_fb<<<init_blocks, TPB, 0, stream>>>(acc, Bf, Af);
        lgcn_spmm_fb<<<sb, TPB, 0, stream>>>(edge_row, edge_col, edge_val, Bf, Af);
        lgcn_accum_fb<<<init_blocks, TPB, 0, stream>>>(acc, Af, Bf);
        lgcn_spmm_fb<<<sb, TPB, 0, stream>>>(edge_row, edge_col, edge_val, Af, Bf);
        lgcn_accum_fb<<<init_blocks, TPB, 0, stream>>>(acc, Bf, nullptr);
        lgcn_dot_fb<<<dot_blocks, TPB, 0, stream>>>(acc, users, items, out);
        return;
    }

    // two-level radix binning + in-place row sort
    lgcn_zero<<<1, TPB, 0, stream>>>(cur1, cur2);
    lgcn_scatter1<<<EB, TPB, 0, stream>>>(edge_row, edge_col, edge_val, cur1, X);
    lgcn_scatter2<<<NC * NCH2, TPB, 0, stream>>>(X, cur1, cur2, Y);
    lgcn_bucket_sort<<<NBUK, TPB, 0, stream>>>(Y, cur2, row_ptr, row_cnt);

    // E0 bf16 (A aliases dead X region)
    lgcn_init_A<<<init_blocks, TPB, 0, stream>>>(user_emb, item_emb, A);

    // layers 1,2 full width (bf16); layer 3 only at sampled rows (f32)
    lgcn_spmm_csr<<<spmm_blocks, TPB, 0, stream>>>(Y, row_ptr, row_cnt, A, B);
    lgcn_spmm_csr<<<spmm_blocks, TPB, 0, stream>>>(Y, row_ptr, row_cnt, B, C);
    lgcn_spmm_sampled<<<samp_blocks, TPB, 0, stream>>>(Y, row_ptr, row_cnt, C,
                                                       users, items, e3);

    // gamma
    lgcn_dot<<<dot_blocks, TPB, 0, stream>>>(user_emb, item_emb, B, C, e3,
                                             users, items, out);
}

// Round 5
// 533.236 us; speedup vs baseline: 10.3485x; 1.4301x over previous
//
#include <hip/hip_runtime.h>
#include <hip/hip_bf16.h>

// LightGCN forward on MI355X — round 14.
// r13 post-mortem: nontemporal stores broke L2 write-combining on scattered
//   8B stores (scatter2: 198us, WRITE 196MB = 3.8x payload, VALU 1.3%) — all
//   nt ops reverted. NEW finding: scatter occupancy 28% is GRID-limited
//   (888 blocks = 3.5/CU at 8 VGPR); preprocessing is latency-bound at 1/3
//   of wave capacity.
// r14: r9 pipeline (526us proven) + (a) CHUNK 8192->2048 in both scatters
//   (3125/3552 blocks -> wave-cap occupancy); (b) bucket_sort RPB 128->64
//   (27.6KB LDS, 5 blocks/CU, 20 waves/CU); (c) r13's ws layout (A,B,C alias
//   dead X; req ~126MB, proven passing).

#define N_USERS  100000
#define N_ITEMS  50000
#define N_TOTAL  150000          // N_USERS + N_ITEMS
#define D        64
#define NNZ      6400000
#define BATCH    4096
#define NELEM    (N_TOTAL * D)   // 9,600,000
#define CHUNK    2048            // scatter chunk (4x more blocks than r9)
#define EB       ((NNZ + CHUNK - 1) / CHUNK)  // 3125

#define NC       37              // coarse buckets (4096 rows each)
#define CROWS    4096
#define CAPC     194600          // coarse capacity (mean 174763 + 48 sigma);
                                 // also sized so X >= A+B+C (57.6MB aliasing)
#define NCH2     ((CAPC + CHUNK - 1) / CHUNK)  // 96 chunks per coarse region
#define NF       64              // fine buckets per coarse (64 rows each)
#define RPB      64
#define NBUK     (NC * NF)       // 2368 fine buckets
#define CAPF     3456            // fine capacity = mean 2731 + 14 sigma

__device__ __forceinline__ float bf2f(unsigned short h) {
    return __uint_as_float(((unsigned int)h) << 16);
}

// ---------- zero cursors ----------
__global__ void lgcn_zero(int* __restrict__ cur1, int* __restrict__ cur2) {
    int i = threadIdx.x;
    if (i < NC) cur1[i] = 0;
    for (int j = i; j < NBUK; j += 256) cur2[j] = 0;
}

// ---------- pass 1: COO -> 37 coarse buckets, direct scatter ----------
// X pair: x = (row_in_coarse<<18) | col  (12b + 18b), y = val bits
__global__ void __launch_bounds__(256)
lgcn_scatter1(const int*   __restrict__ rows,
              const int*   __restrict__ cols,
              const float* __restrict__ vals,
              int*         __restrict__ cur1,
              int2*        __restrict__ X) {
    __shared__ int h[NC];
    __shared__ int gb[NC];
    int tid = threadIdx.x;
    int s = blockIdx.x * CHUNK;
    int e_end = s + CHUNK; if (e_end > NNZ) e_end = NNZ;

    if (tid < NC) h[tid] = 0;
    __syncthreads();
    for (int e = s + tid; e < e_end; e += 256)
        atomicAdd(&h[rows[e] >> 12], 1);
    __syncthreads();
    if (tid < NC) {
        int c = h[tid];
        gb[tid] = c ? atomicAdd(&cur1[tid], c) : 0;
        h[tid] = 0;
    }
    __syncthreads();
    for (int e = s + tid; e < e_end; e += 256) {
        int r = rows[e];
        int c = r >> 12;
        int rank = atomicAdd(&h[c], 1);
        int o = gb[c] + rank;
        int2 p;
        p.x = ((r & 4095) << 18) | cols[e];
        p.y = __float_as_int(vals[e]);
        X[(o < CAPC) ? ((size_t)c * CAPC + o) : ((size_t)NC * CAPC)] = p;
    }
}

// ---------- pass 2: coarse region -> 64 fine buckets, direct scatter ----------
__global__ void __launch_bounds__(256)
lgcn_scatter2(const int2* __restrict__ X,
              const int*  __restrict__ cur1,
              int*        __restrict__ cur2,
              int2*       __restrict__ Y) {
    int c = blockIdx.x / NCH2;
    int ch = blockIdx.x % NCH2;
    int cnt_c = cur1[c]; if (cnt_c > CAPC) cnt_c = CAPC;
    int s = ch * CHUNK;
    int n = cnt_c - s; if (n > CHUNK) n = CHUNK;
    if (n <= 0) return;                       // uniform per block

    __shared__ int h[NF];
    __shared__ int gb[NF];
    int tid = threadIdx.x;
    size_t base = (size_t)c * CAPC + s;

    if (tid < NF) h[tid] = 0;
    __syncthreads();
    for (int i = tid; i < n; i += 256)
        atomicAdd(&h[X[base + i].x >> 24], 1);
    __syncthreads();
    if (tid < NF) {
        int cc = h[tid];
        gb[tid] = cc ? atomicAdd(&cur2[c * NF + tid], cc) : 0;
        h[tid] = 0;
    }
    __syncthreads();
    for (int i = tid; i < n; i += 256) {
        int2 p = X[base + i];
        int f = p.x >> 24;                    // fine6 = lr12 >> 6
        int rank = atomicAdd(&h[f], 1);
        int o = gb[f] + rank;
        int2 q;
        q.x = p.x & 0x00FFFFFF;               // keep lr6 (bits 18..23) + col18
        q.y = p.y;
        Y[(o < CAPF) ? ((size_t)(c * NF + f) * CAPF + o)
                     : ((size_t)NBUK * CAPF)] = q;
    }
}

// ---------- pass 3: in-place per-fine-bucket row-exact sort; emit CSR ----------
__global__ void __launch_bounds__(256)
lgcn_bucket_sort(int2* __restrict__ Y,
                 const int* __restrict__ cur2,
                 int* __restrict__ row_ptr,
                 int* __restrict__ row_cnt) {
    __shared__ int2 buf[CAPF];         // 27.6 KB -> 5 blocks/CU
    __shared__ int  h[RPB];
    __shared__ int  base[RPB];
    int tid = threadIdx.x;
    int fb = blockIdx.x;
    size_t start = (size_t)fb * CAPF;
    int cnt = cur2[fb]; if (cnt > CAPF) cnt = CAPF;

    for (int i = tid; i < cnt; i += 256) buf[i] = Y[start + i];
    if (tid < RPB) h[tid] = 0;
    __syncthreads();
    for (int i = tid; i < cnt; i += 256) atomicAdd(&h[buf[i].x >> 18], 1);
    __syncthreads();

    // exclusive scan of h[0..63]
    int v = (tid < RPB) ? h[tid] : 0;
    int sum = v;
    #pragma unroll
    for (int off = 1; off < RPB; off <<= 1) {
        if (tid < RPB) base[tid] = sum;
        __syncthreads();
        if (tid >= off && tid < RPB) sum += base[tid - off];
        __syncthreads();
    }
    if (tid < RPB) {
        int excl = sum - v;
        base[tid] = excl;
        int gr = (fb >> 6) * CROWS + (fb & 63) * RPB + tid;
        if (gr < N_TOTAL) {
            row_ptr[gr] = (int)start + excl;
            row_cnt[gr] = v;
        }
        h[tid] = 0;                    // reuse as per-row cursor
    }
    __syncthreads();

    for (int i = tid; i < cnt; i += 256) {
        int2 p = buf[i];
        int lr = p.x >> 18;
        int rank = atomicAdd(&h[lr], 1);
        Y[start + base[lr] + rank] = p;   // in place; 27KB window -> L2
    }
}

// ---------- init A = bf16(concat(user,item)) (after pass 2: A aliases X) ------
__global__ void lgcn_init_A(const float* __restrict__ user_emb,
                            const float* __restrict__ item_emb,
                            unsigned short* __restrict__ A) {
    int i = blockIdx.x * blockDim.x + threadIdx.x;
    if (i < NELEM) {
        float v = (i < N_USERS * D) ? user_emb[i] : item_emb[i - N_USERS * D];
        __hip_bfloat16 b = __float2bfloat16(v);   // RNE
        A[i] = *(unsigned short*)&b;
    }
}

// ---------- SpMM: wave per row, dual-edge (2 edges per wave-iter) ----------
// lane = 32*half + hl; half h processes edge (jj+2k+h); lane loads a dword
// (dims 2hl, 2hl+1). Cross-half combine via shfl_xor(32); packed uint stores.
__global__ void lgcn_spmm_csr(const int2* __restrict__ pairs,
                              const int*  __restrict__ row_ptr,
                              const int*  __restrict__ row_cnt,
                              const unsigned short* __restrict__ cur,
                              unsigned short* __restrict__ nxt) {
    const unsigned int* __restrict__ cur32 = (const unsigned int*)cur;
    int t = blockIdx.x * blockDim.x + threadIdx.x;
    int r = t >> 6;
    int lane = t & 63;
    if (r >= N_TOTAL) return;
    int halfid = lane >> 5;
    int hl = lane & 31;
    int start = row_ptr[r];
    int cnt   = row_cnt[r];
    float sA = 0.f, sB = 0.f;
    for (int base = 0; base < cnt; base += 64) {
        int idx = base + lane;
        int2 p = {0, 0};
        if (idx < cnt) p = pairs[start + idx];     // coalesced dwordx2
        int m = cnt - base; if (m > 64) m = 64;
        int jj = 0;
        for (; jj + 8 <= m; jj += 8) {             // 8 edges, unguarded
            #pragma unroll
            for (int k = 0; k < 4; k++) {
                int sel = jj + 2 * k + halfid;
                int   c = __shfl(p.x, sel, 64);
                float v = __int_as_float(__shfl(p.y, sel, 64));
                unsigned int u = cur32[(c & 0x3FFFF) * 32 + hl];
                sA = fmaf(v, __uint_as_float(u << 16), sA);
                sB = fmaf(v, __uint_as_float(u & 0xFFFF0000u), sB);
            }
        }
        if (jj < m) {                              // tail: guarded (p=0 beyond cnt)
            #pragma unroll
            for (int k = 0; k < 4; k++) {
                int sel = jj + 2 * k + halfid;
                int   c = __shfl(p.x, sel, 64);
                float v = __int_as_float(__shfl(p.y, sel, 64));
                if (sel >= m) v = 0.f;
                unsigned int u = cur32[(c & 0x3FFFF) * 32 + hl];
                sA = fmaf(v, __uint_as_float(u << 16), sA);
                sB = fmaf(v, __uint_as_float(u & 0xFFFF0000u), sB);
            }
        }
    }
    sA += __shfl_xor(sA, 32, 64);
    sB += __shfl_xor(sB, 32, 64);
    if (halfid == 0) {
        __hip_bfloat16 a = __float2bfloat16(sA);   // RNE
        __hip_bfloat16 b = __float2bfloat16(sB);
        unsigned int lo = *(unsigned short*)&a;
        unsigned int hi = *(unsigned short*)&b;
        ((unsigned int*)nxt)[r * 32 + hl] = lo | (hi << 16);  // half-wave 128B
    }
}

// ---------- layer 3 at sampled rows only: e3[s,:] = (A @ E2)[row(s),:] (f32) ----
__global__ void lgcn_spmm_sampled(const int2* __restrict__ pairs,
                                  const int*  __restrict__ row_ptr,
                                  const int*  __restrict__ row_cnt,
                                  const unsigned short* __restrict__ cur,
                                  const int* __restrict__ users,
                                  const int* __restrict__ items,
                                  float* __restrict__ e3) {
    int t = blockIdx.x * blockDim.x + threadIdx.x;
    int s = t >> 6;
    int lane = t & 63;
    if (s >= 2 * BATCH) return;
    int r = (s < BATCH) ? users[s] : (N_USERS + items[s - BATCH]);
    int start = row_ptr[r];
    int cnt   = row_cnt[r];
    float sum0 = 0.f, sum1 = 0.f;
    for (int base = 0; base < cnt; base += 64) {
        int idx = base + lane;
        int2 p = {0, 0};
        if (idx < cnt) p = pairs[start + idx];
        int m = cnt - base; if (m > 64) m = 64;
        int j = 0;
        for (; j + 8 <= m; j += 8) {
            float acc[8];
            #pragma unroll
            for (int k = 0; k < 8; k++) {
                int   c = __shfl(p.x, j + k, 64);
                float v = __int_as_float(__shfl(p.y, j + k, 64));
                acc[k] = v * bf2f(cur[(c & 0x3FFFF) * D + lane]);
            }
            sum0 += acc[0] + acc[2] + acc[4] + acc[6];
            sum1 += acc[1] + acc[3] + acc[5] + acc[7];
        }
        for (; j < m; j++) {
            int   c = __shfl(p.x, j, 64);
            float v = __int_as_float(__shfl(p.y, j, 64));
            sum0 += v * bf2f(cur[(c & 0x3FFFF) * D + lane]);
        }
    }
    e3[s * D + lane] = sum0 + sum1;
}

// ---------- dot: gamma = <E0+E1+E2+E3>_u . <E0+E1+E2+E3>_i / 16 ----------
__global__ void lgcn_dot(const float* __restrict__ user_emb,
                         const float* __restrict__ item_emb,
                         const unsigned short* __restrict__ E1,
                         const unsigned short* __restrict__ E2,
                         const float* __restrict__ e3,
                         const int* __restrict__ users,
                         const int* __restrict__ items,
                         float* __restrict__ out) {
    int t = blockIdx.x * blockDim.x + threadIdx.x;
    int b = t >> 6;
    int d = t & 63;
    if (b < BATCH) {
        int u  = users[b];
        int it = items[b];
        int ur = u * D + d;
        int ir = (N_USERS + it) * D + d;
        float au = user_emb[ur] + bf2f(E1[ur]) + bf2f(E2[ur]) + e3[b * D + d];
        float ai = item_emb[it * D + d] + bf2f(E1[ir]) + bf2f(E2[ir])
                 + e3[(BATCH + b) * D + d];
        float p = au * ai;
        #pragma unroll
        for (int off = 32; off; off >>= 1) p += __shfl_down(p, off, 64);
        if (d == 0) out[b] = p * (1.0f / 16.0f);
    }
}

// ---------- round-1 fallback (atomic scatter) if ws too small ----------
__global__ void lgcn_init_fb(const float* __restrict__ user_emb,
                             const float* __restrict__ item_emb,
                             float* __restrict__ acc,
                             float* __restrict__ cur,
                             float* __restrict__ nxt) {
    int i = blockIdx.x * blockDim.x + threadIdx.x;
    if (i < NELEM) {
        float v = (i < N_USERS * D) ? user_emb[i] : item_emb[i - N_USERS * D];
        acc[i] = v; cur[i] = v; nxt[i] = 0.0f;
    }
}
__global__ void lgcn_spmm_fb(const int* __restrict__ rows,
                             const int* __restrict__ cols,
                             const float* __restrict__ vals,
                             const float* __restrict__ cur,
                             float* __restrict__ nxt) {
    long long t = (long long)blockIdx.x * blockDim.x + threadIdx.x;
    int e = (int)(t >> 6);
    int d = (int)(t & 63);
    if (e < NNZ) {
        float x = cur[cols[e] * D + d];
        unsafeAtomicAdd(&nxt[rows[e] * D + d], vals[e] * x);
    }
}
__global__ void lgcn_accum_fb(float* __restrict__ acc,
                              const float* __restrict__ src,
                              float* __restrict__ to_zero) {
    int i = blockIdx.x * blockDim.x + threadIdx.x;
    if (i < NELEM) {
        acc[i] += src[i];
        if (to_zero) to_zero[i] = 0.0f;
    }
}
__global__ void lgcn_dot_fb(const float* __restrict__ acc,
                            const int* __restrict__ users,
                            const int* __restrict__ items,
                            float* __restrict__ out) {
    int t = blockIdx.x * blockDim.x + threadIdx.x;
    int b = t >> 6;
    int d = t & 63;
    if (b < BATCH) {
        int u  = users[b];
        int it = items[b];
        float p = acc[u * D + d] * acc[(N_USERS + it) * D + d];
        #pragma unroll
        for (int off = 32; off; off >>= 1) p += __shfl_down(p, off, 64);
        if (d == 0) out[b] = p * (1.0f / 16.0f);
    }
}

extern "C" void kernel_launch(void* const* d_in, const int* in_sizes, int n_in,
                              void* d_out, int out_size, void* d_ws, size_t ws_size,
                              hipStream_t stream) {
    const float* user_emb = (const float*)d_in[0];
    const float* item_emb = (const float*)d_in[1];
    const int*   edge_row = (const int*)d_in[2];
    const int*   edge_col = (const int*)d_in[3];
    const float* edge_val = (const float*)d_in[4];
    const int*   users    = (const int*)d_in[5];
    const int*   items    = (const int*)d_in[6];
    float*       out      = (float*)d_out;

    const int TPB = 256;
    int init_blocks = (NELEM + TPB - 1) / TPB;
    int spmm_blocks = (N_TOTAL * 64 + TPB - 1) / TPB;       // wave per row
    int samp_blocks = (2 * BATCH * 64 + TPB - 1) / TPB;     // wave per sampled row
    int dot_blocks  = (BATCH * 64 + TPB - 1) / TPB;

    // workspace layout (~126.4MB, proven passing in r13):
    //   X (coarse pairs, +1 sink) — dead after pass 2; A,B,C bf16 ALL alias it
    //     (CAPC sized so X bytes >= 3*NELEM*2 = 57.6MB)
    //   Y (fine pairs, +1 sink)   — final row-sorted CSR pairs (in-place sort)
    //   e3 f32, cursors, row_ptr/row_cnt
    int2* X = (int2*)d_ws;                              // NC*CAPC + 1
    int2* Y = X + (size_t)NC * CAPC + 1;                // NBUK*CAPF + 1
    float* e3 = (float*)(Y + (size_t)NBUK * CAPF + 1);  // 2*BATCH*D
    int* cur1 = (int*)(e3 + 2 * BATCH * D);             // NC
    int* cur2 = cur1 + NC;                              // NBUK
    int* row_ptr = cur2 + NBUK;                         // NBUK*RPB
    int* row_cnt = row_ptr + NBUK * RPB;                // NBUK*RPB
    size_t req = (size_t)((char*)(row_cnt + NBUK * RPB) - (char*)d_ws);
    unsigned short* A = (unsigned short*)X;             // alias: init after pass 2
    unsigned short* B = A + NELEM;                      // alias
    unsigned short* C = B + NELEM;                      // alias: 57.6MB <= X bytes

    if (ws_size < req && ws_size >= (size_t)3 * NELEM * 4) {
        // fallback: round-1 atomic path (needs only 3*NELEM floats)
        float* acc = (float*)d_ws;
        float* Af  = acc + NELEM;
        float* Bf  = Af + NELEM;
        long long st = (long long)NNZ * 64;
        int sb = (int)((st + TPB - 1) / TPB);
        lgcn_init_fb<<<init_blocks, TPB, 0, stream>>>(user_emb, item_emb, acc, Af, Bf);
        lgcn_spmm_fb<<<sb, TPB, 0, stream>>>(edge_row, edge_col, edge_val, Af, Bf);
        lgcn_accum_fb<<<init_blocks, TPB, 0, stream>>>(acc, Bf, Af);
        lgcn_spmm_fb<<<sb, TPB, 0, stream>>>(edge_row, edge_col, edge_val, Bf, Af);
        lgcn_accum_fb<<<init_blocks, TPB, 0, stream>>>(acc, Af, Bf);
        lgcn_spmm_fb<<<sb, TPB, 0, stream>>>(edge_row, edge_col, edge_val, Af, Bf);
        lgcn_accum_fb<<<init_blocks, TPB, 0, stream>>>(acc, Bf, nullptr);
        lgcn_dot_fb<<<dot_blocks, TPB, 0, stream>>>(acc, users, items, out);
        return;
    }

    // two-level radix binning + in-place row sort
    lgcn_zero<<<1, TPB, 0, stream>>>(cur1, cur2);
    lgcn_scatter1<<<EB, TPB, 0, stream>>>(edge_row, edge_col, edge_val, cur1, X);
    lgcn_scatter2<<<NC * NCH2, TPB, 0, stream>>>(X, cur1, cur2, Y);
    lgcn_bucket_sort<<<NBUK, TPB, 0, stream>>>(Y, cur2, row_ptr, row_cnt);

    // E0 bf16 (A aliases dead X region)
    lgcn_init_A<<<init_blocks, TPB, 0, stream>>>(user_emb, item_emb, A);

    // layers 1,2 full width (bf16); layer 3 only at sampled rows (f32)
    lgcn_spmm_csr<<<spmm_blocks, TPB, 0, stream>>>(Y, row_ptr, row_cnt, A, B);
    lgcn_spmm_csr<<<spmm_blocks, TPB, 0, stream>>>(Y, row_ptr, row_cnt, B, C);
    lgcn_spmm_sampled<<<samp_blocks, TPB, 0, stream>>>(Y, row_ptr, row_cnt, C,
                                                       users, items, e3);

    // gamma
    lgcn_dot<<<dot_blocks, TPB, 0, stream>>>(user_emb, item_emb, B, C, e3,
                                             users, items, out);
}

// Round 6
// 520.736 us; speedup vs baseline: 10.5969x; 1.0240x over previous
//
#include <hip/hip_runtime.h>
#include <hip/hip_bf16.h>

// LightGCN forward on MI355X — round 15.
// r14 post-mortem: CHUNK 8192->2048 occupancy theory FALSIFIED (533 vs 526,
//   predicted -80us) — scatters are store/latency-structure-bound, not
//   occupancy-bound. CHUNK reverted to 8192. spmm stable: VALU 53%, HBM 45%.
// r15: spmm issue-rate attack, evidence: VALU-busy 56us ~= HBM floor 56us.
//   (a) LDS-stage the 64-pair chunk per wave (512B slice): dual-edge broadcast
//       becomes ds_read_b64 at immediate offset — replaces 2 ds_bpermute + 2
//       addr VALU per k-iter; tail guards vanish ({0,0} stage entries).
//   (b) Y pairs re-packed as (col<<7)|lr6: x & 0xFFFFFF80 IS the table-row
//       byte offset; per-lane +hl*4 folds into hoisted base pointer.
//   ~12-14 -> ~7-8 VALU/k-iter, DS pipe halved, same FETCH.

#define N_USERS  100000
#define N_ITEMS  50000
#define N_TOTAL  150000          // N_USERS + N_ITEMS
#define D        64
#define NNZ      6400000
#define BATCH    4096
#define NELEM    (N_TOTAL * D)   // 9,600,000
#define CHUNK    8192
#define EB       ((NNZ + CHUNK - 1) / CHUNK)  // 782

#define NC       37              // coarse buckets (4096 rows each)
#define CROWS    4096
#define CAPC     194600          // coarse capacity (mean 174763 + 48 sigma);
                                 // also sized so X >= A+B+C (57.6MB aliasing)
#define NCH2     ((CAPC + CHUNK - 1) / CHUNK)  // 24 chunks per coarse region
#define NF       64              // fine buckets per coarse (64 rows each)
#define RPB      64
#define NBUK     (NC * NF)       // 2368 fine buckets
#define CAPF     3456            // fine capacity = mean 2731 + 14 sigma

__device__ __forceinline__ float bf2f(unsigned short h) {
    return __uint_as_float(((unsigned int)h) << 16);
}

// ---------- zero cursors ----------
__global__ void lgcn_zero(int* __restrict__ cur1, int* __restrict__ cur2) {
    int i = threadIdx.x;
    if (i < NC) cur1[i] = 0;
    for (int j = i; j < NBUK; j += 256) cur2[j] = 0;
}

// ---------- pass 1: COO -> 37 coarse buckets, direct scatter ----------
// X pair: x = (row_in_coarse<<18) | col  (12b + 18b), y = val bits
__global__ void __launch_bounds__(256)
lgcn_scatter1(const int*   __restrict__ rows,
              const int*   __restrict__ cols,
              const float* __restrict__ vals,
              int*         __restrict__ cur1,
              int2*        __restrict__ X) {
    __shared__ int h[NC];
    __shared__ int gb[NC];
    int tid = threadIdx.x;
    int s = blockIdx.x * CHUNK;
    int e_end = s + CHUNK; if (e_end > NNZ) e_end = NNZ;

    if (tid < NC) h[tid] = 0;
    __syncthreads();
    for (int e = s + tid; e < e_end; e += 256)
        atomicAdd(&h[rows[e] >> 12], 1);
    __syncthreads();
    if (tid < NC) {
        int c = h[tid];
        gb[tid] = c ? atomicAdd(&cur1[tid], c) : 0;
        h[tid] = 0;
    }
    __syncthreads();
    for (int e = s + tid; e < e_end; e += 256) {
        int r = rows[e];
        int c = r >> 12;
        int rank = atomicAdd(&h[c], 1);
        int o = gb[c] + rank;
        int2 p;
        p.x = ((r & 4095) << 18) | cols[e];
        p.y = __float_as_int(vals[e]);
        X[(o < CAPC) ? ((size_t)c * CAPC + o) : ((size_t)NC * CAPC)] = p;
    }
}

// ---------- pass 2: coarse region -> 64 fine buckets, direct scatter ----------
// Y pair: x = (col18 << 7) | lr6  (pre-scaled column: x & ~127 = row byte off)
__global__ void __launch_bounds__(256)
lgcn_scatter2(const int2* __restrict__ X,
              const int*  __restrict__ cur1,
              int*        __restrict__ cur2,
              int2*       __restrict__ Y) {
    int c = blockIdx.x / NCH2;
    int ch = blockIdx.x % NCH2;
    int cnt_c = cur1[c]; if (cnt_c > CAPC) cnt_c = CAPC;
    int s = ch * CHUNK;
    int n = cnt_c - s; if (n > CHUNK) n = CHUNK;
    if (n <= 0) return;                       // uniform per block

    __shared__ int h[NF];
    __shared__ int gb[NF];
    int tid = threadIdx.x;
    size_t base = (size_t)c * CAPC + s;

    if (tid < NF) h[tid] = 0;
    __syncthreads();
    for (int i = tid; i < n; i += 256)
        atomicAdd(&h[X[base + i].x >> 24], 1);
    __syncthreads();
    if (tid < NF) {
        int cc = h[tid];
        gb[tid] = cc ? atomicAdd(&cur2[c * NF + tid], cc) : 0;
        h[tid] = 0;
    }
    __syncthreads();
    for (int i = tid; i < n; i += 256) {
        int2 p = X[base + i];
        int f = p.x >> 24;                    // fine6 = lr12 >> 6
        int rank = atomicAdd(&h[f], 1);
        int o = gb[f] + rank;
        int2 q;
        q.x = ((p.x & 0x3FFFF) << 7) | ((p.x >> 18) & 63);  // col<<7 | lr6
        q.y = p.y;
        Y[(o < CAPF) ? ((size_t)(c * NF + f) * CAPF + o)
                     : ((size_t)NBUK * CAPF)] = q;
    }
}

// ---------- pass 3: in-place per-fine-bucket row-exact sort; emit CSR ----------
__global__ void __launch_bounds__(256)
lgcn_bucket_sort(int2* __restrict__ Y,
                 const int* __restrict__ cur2,
                 int* __restrict__ row_ptr,
                 int* __restrict__ row_cnt) {
    __shared__ int2 buf[CAPF];         // 27.6 KB -> 5 blocks/CU
    __shared__ int  h[RPB];
    __shared__ int  base[RPB];
    int tid = threadIdx.x;
    int fb = blockIdx.x;
    size_t start = (size_t)fb * CAPF;
    int cnt = cur2[fb]; if (cnt > CAPF) cnt = CAPF;

    for (int i = tid; i < cnt; i += 256) buf[i] = Y[start + i];
    if (tid < RPB) h[tid] = 0;
    __syncthreads();
    for (int i = tid; i < cnt; i += 256) atomicAdd(&h[buf[i].x & 63], 1);
    __syncthreads();

    // exclusive scan of h[0..63]
    int v = (tid < RPB) ? h[tid] : 0;
    int sum = v;
    #pragma unroll
    for (int off = 1; off < RPB; off <<= 1) {
        if (tid < RPB) base[tid] = sum;
        __syncthreads();
        if (tid >= off && tid < RPB) sum += base[tid - off];
        __syncthreads();
    }
    if (tid < RPB) {
        int excl = sum - v;
        base[tid] = excl;
        int gr = (fb >> 6) * CROWS + (fb & 63) * RPB + tid;
        if (gr < N_TOTAL) {
            row_ptr[gr] = (int)start + excl;
            row_cnt[gr] = v;
        }
        h[tid] = 0;                    // reuse as per-row cursor
    }
    __syncthreads();

    for (int i = tid; i < cnt; i += 256) {
        int2 p = buf[i];
        int lr = p.x & 63;
        int rank = atomicAdd(&h[lr], 1);
        Y[start + base[lr] + rank] = p;   // in place; 27KB window -> L2
    }
}

// ---------- init A = bf16(concat(user,item)) (after pass 2: A aliases X) ------
__global__ void lgcn_init_A(const float* __restrict__ user_emb,
                            const float* __restrict__ item_emb,
                            unsigned short* __restrict__ A) {
    int i = blockIdx.x * blockDim.x + threadIdx.x;
    if (i < NELEM) {
        float v = (i < N_USERS * D) ? user_emb[i] : item_emb[i - N_USERS * D];
        __hip_bfloat16 b = __float2bfloat16(v);   // RNE
        A[i] = *(unsigned short*)&b;
    }
}

// ---------- SpMM: wave per row, dual-edge, LDS-staged pair broadcast ----------
// Pair chunk staged in per-wave LDS slice (512B); dual-edge reads via
// ds_read_b64 at immediate offsets (unrolled). x & ~127 = table row byte off;
// per-lane +hl*4 folded into base pointer. Beyond-cnt entries are {0,0} -> v=0.
__global__ void __launch_bounds__(256)
lgcn_spmm_csr(const int2* __restrict__ pairs,
              const int*  __restrict__ row_ptr,
              const int*  __restrict__ row_cnt,
              const unsigned short* __restrict__ cur,
              unsigned short* __restrict__ nxt) {
    __shared__ int2 stage[4][64];
    int t = blockIdx.x * blockDim.x + threadIdx.x;
    int r = t >> 6;
    int lane = t & 63;
    if (r >= N_TOTAL) return;
    int halfid = lane >> 5;
    int hl = lane & 31;
    const char* __restrict__ curb = (const char*)cur + hl * 4;  // lane-folded
    int2* st = stage[threadIdx.x >> 6];
    int start = row_ptr[r];
    int cnt   = row_cnt[r];
    float sA = 0.f, sB = 0.f;
    for (int base = 0; base < cnt; base += 64) {
        int idx = base + lane;
        int2 p = {0, 0};
        if (idx < cnt) p = pairs[start + idx];     // coalesced dwordx2
        st[lane] = p;                              // per-wave slice, no barrier
        int m = cnt - base; if (m > 64) m = 64;
        for (int jj = 0; jj < m; jj += 8) {        // 8 edges per unrolled body
            #pragma unroll
            for (int k = 0; k < 4; k++) {
                int2 q = st[jj + 2 * k + halfid];  // ds_read_b64 broadcast
                float v = __int_as_float(q.y);     // 0 beyond cnt
                unsigned off = (unsigned)q.x & 0xFFFFFF80u;   // col*128
                unsigned u = *(const unsigned*)(curb + off);
                sA = fmaf(v, __uint_as_float(u << 16), sA);
                sB = fmaf(v, __uint_as_float(u & 0xFFFF0000u), sB);
            }
        }
    }
    sA += __shfl_xor(sA, 32, 64);
    sB += __shfl_xor(sB, 32, 64);
    if (halfid == 0) {
        __hip_bfloat16 a = __float2bfloat16(sA);   // RNE
        __hip_bfloat16 b = __float2bfloat16(sB);
        unsigned int lo = *(unsigned short*)&a;
        unsigned int hi = *(unsigned short*)&b;
        ((unsigned int*)nxt)[r * 32 + hl] = lo | (hi << 16);  // half-wave 128B
    }
}

// ---------- layer 3 at sampled rows only: e3[s,:] = (A @ E2)[row(s),:] (f32) ----
__global__ void __launch_bounds__(256)
lgcn_spmm_sampled(const int2* __restrict__ pairs,
                  const int*  __restrict__ row_ptr,
                  const int*  __restrict__ row_cnt,
                  const unsigned short* __restrict__ cur,
                  const int* __restrict__ users,
                  const int* __restrict__ items,
                  float* __restrict__ e3) {
    __shared__ int2 stage[4][64];
    int t = blockIdx.x * blockDim.x + threadIdx.x;
    int s = t >> 6;
    int lane = t & 63;
    if (s >= 2 * BATCH) return;
    int r = (s < BATCH) ? users[s] : (N_USERS + items[s - BATCH]);
    const char* __restrict__ curb = (const char*)cur + lane * 2;  // bf16 dim
    int2* st = stage[threadIdx.x >> 6];
    int start = row_ptr[r];
    int cnt   = row_cnt[r];
    float sum0 = 0.f, sum1 = 0.f;
    for (int base = 0; base < cnt; base += 64) {
        int idx = base + lane;
        int2 p = {0, 0};
        if (idx < cnt) p = pairs[start + idx];
        st[lane] = p;
        int m = cnt - base; if (m > 64) m = 64;
        for (int j = 0; j < m; j += 8) {
            #pragma unroll
            for (int k = 0; k < 8; k++) {
                int2 q = st[j + k];                // broadcast
                float v = __int_as_float(q.y);     // 0 beyond cnt
                unsigned off = (unsigned)q.x & 0xFFFFFF80u;
                unsigned short u = *(const unsigned short*)(curb + off);
                if (k & 1) sum1 = fmaf(v, bf2f(u), sum1);
                else       sum0 = fmaf(v, bf2f(u), sum0);
            }
        }
    }
    e3[s * D + lane] = sum0 + sum1;
}

// ---------- dot: gamma = <E0+E1+E2+E3>_u . <E0+E1+E2+E3>_i / 16 ----------
__global__ void lgcn_dot(const float* __restrict__ user_emb,
                         const float* __restrict__ item_emb,
                         const unsigned short* __restrict__ E1,
                         const unsigned short* __restrict__ E2,
                         const float* __restrict__ e3,
                         const int* __restrict__ users,
                         const int* __restrict__ items,
                         float* __restrict__ out) {
    int t = blockIdx.x * blockDim.x + threadIdx.x;
    int b = t >> 6;
    int d = t & 63;
    if (b < BATCH) {
        int u  = users[b];
        int it = items[b];
        int ur = u * D + d;
        int ir = (N_USERS + it) * D + d;
        float au = user_emb[ur] + bf2f(E1[ur]) + bf2f(E2[ur]) + e3[b * D + d];
        float ai = item_emb[it * D + d] + bf2f(E1[ir]) + bf2f(E2[ir])
                 + e3[(BATCH + b) * D + d];
        float p = au * ai;
        #pragma unroll
        for (int off = 32; off; off >>= 1) p += __shfl_down(p, off, 64);
        if (d == 0) out[b] = p * (1.0f / 16.0f);
    }
}

// ---------- round-1 fallback (atomic scatter) if ws too small ----------
__global__ void lgcn_init_fb(const float* __restrict__ user_emb,
                             const float* __restrict__ item_emb,
                             float* __restrict__ acc,
                             float* __restrict__ cur,
                             float* __restrict__ nxt) {
    int i = blockIdx.x * blockDim.x + threadIdx.x;
    if (i < NELEM) {
        float v = (i < N_USERS * D) ? user_emb[i] : item_emb[i - N_USERS * D];
        acc[i] = v; cur[i] = v; nxt[i] = 0.0f;
    }
}
__global__ void lgcn_spmm_fb(const int* __restrict__ rows,
                             const int* __restrict__ cols,
                             const float* __restrict__ vals,
                             const float* __restrict__ cur,
                             float* __restrict__ nxt) {
    long long t = (long long)blockIdx.x * blockDim.x + threadIdx.x;
    int e = (int)(t >> 6);
    int d = (int)(t & 63);
    if (e < NNZ) {
        float x = cur[cols[e] * D + d];
        unsafeAtomicAdd(&nxt[rows[e] * D + d], vals[e] * x);
    }
}
__global__ void lgcn_accum_fb(float* __restrict__ acc,
                              const float* __restrict__ src,
                              float* __restrict__ to_zero) {
    int i = blockIdx.x * blockDim.x + threadIdx.x;
    if (i < NELEM) {
        acc[i] += src[i];
        if (to_zero) to_zero[i] = 0.0f;
    }
}
__global__ void lgcn_dot_fb(const float* __restrict__ acc,
                            const int* __restrict__ users,
                            const int* __restrict__ items,
                            float* __restrict__ out) {
    int t = blockIdx.x * blockDim.x + threadIdx.x;
    int b = t >> 6;
    int d = t & 63;
    if (b < BATCH) {
        int u  = users[b];
        int it = items[b];
        float p = acc[u * D + d] * acc[(N_USERS + it) * D + d];
        #pragma unroll
        for (int off = 32; off; off >>= 1) p += __shfl_down(p, off, 64);
        if (d == 0) out[b] = p * (1.0f / 16.0f);
    }
}

extern "C" void kernel_launch(void* const* d_in, const int* in_sizes, int n_in,
                              void* d_out, int out_size, void* d_ws, size_t ws_size,
                              hipStream_t stream) {
    const float* user_emb = (const float*)d_in[0];
    const float* item_emb = (const float*)d_in[1];
    const int*   edge_row = (const int*)d_in[2];
    const int*   edge_col = (const int*)d_in[3];
    const float* edge_val = (const float*)d_in[4];
    const int*   users    = (const int*)d_in[5];
    const int*   items    = (const int*)d_in[6];
    float*       out      = (float*)d_out;

    const int TPB = 256;
    int init_blocks = (NELEM + TPB - 1) / TPB;
    int spmm_blocks = (N_TOTAL * 64 + TPB - 1) / TPB;       // wave per row
    int samp_blocks = (2 * BATCH * 64 + TPB - 1) / TPB;     // wave per sampled row
    int dot_blocks  = (BATCH * 64 + TPB - 1) / TPB;

    // workspace layout (~126.4MB, proven passing):
    //   X (coarse pairs, +1 sink) — dead after pass 2; A,B,C bf16 ALL alias it
    //     (CAPC sized so X bytes >= 3*NELEM*2 = 57.6MB)
    //   Y (fine pairs, +1 sink)   — final row-sorted CSR pairs (in-place sort)
    //   e3 f32, cursors, row_ptr/row_cnt
    int2* X = (int2*)d_ws;                              // NC*CAPC + 1
    int2* Y = X + (size_t)NC * CAPC + 1;                // NBUK*CAPF + 1
    float* e3 = (float*)(Y + (size_t)NBUK * CAPF + 1);  // 2*BATCH*D
    int* cur1 = (int*)(e3 + 2 * BATCH * D);             // NC
    int* cur2 = cur1 + NC;                              // NBUK
    int* row_ptr = cur2 + NBUK;                         // NBUK*RPB
    int* row_cnt = row_ptr + NBUK * RPB;                // NBUK*RPB
    size_t req = (size_t)((char*)(row_cnt + NBUK * RPB) - (char*)d_ws);
    unsigned short* A = (unsigned short*)X;             // alias: init after pass 2
    unsigned short* B = A + NELEM;                      // alias
    unsigned short* C = B + NELEM;                      // alias: 57.6MB <= X bytes

    if (ws_size < req && ws_size >= (size_t)3 * NELEM * 4) {
        // fallback: round-1 atomic path (needs only 3*NELEM floats)
        float* acc = (float*)d_ws;
        float* Af  = acc + NELEM;
        float* Bf  = Af + NELEM;
        long long st = (long long)NNZ * 64;
        int sb = (int)((st + TPB - 1) / TPB);
        lgcn_init_fb<<<init_blocks, TPB, 0, stream>>>(user_emb, item_emb, acc, Af, Bf);
        lgcn_spmm_fb<<<sb, TPB, 0, stream>>>(edge_row, edge_col, edge_val, Af, Bf);
        lgcn_accum_fb<<<init_blocks, TPB, 0, stream>>>(acc, Bf, Af);
        lgcn_spmm_fb<<<sb, TPB, 0, stream>>>(edge_row, edge_col, edge_val, Bf, Af);
        lgcn_accum_fb<<<init_blocks, TPB, 0, stream>>>(acc, Af, Bf);
        lgcn_spmm_fb<<<sb, TPB, 0, stream>>>(edge_row, edge_col, edge_val, Af, Bf);
        lgcn_accum_fb<<<init_blocks, TPB, 0, stream>>>(acc, Bf, nullptr);
        lgcn_dot_fb<<<dot_blocks, TPB, 0, stream>>>(acc, users, items, out);
        return;
    }

    // two-level radix binning + in-place row sort
    lgcn_zero<<<1, TPB, 0, stream>>>(cur1, cur2);
    lgcn_scatter1<<<EB, TPB, 0, stream>>>(edge_row, edge_col, edge_val, cur1, X);
    lgcn_scatter2<<<NC * NCH2, TPB, 0, stream>>>(X, cur1, cur2, Y);
    lgcn_bucket_sort<<<NBUK, TPB, 0, stream>>>(Y, cur2, row_ptr, row_cnt);

    // E0 bf16 (A aliases dead X region)
    lgcn_init_A<<<init_blocks, TPB, 0, stream>>>(user_emb, item_emb, A);

    // layers 1,2 full width (bf16); layer 3 only at sampled rows (f32)
    lgcn_spmm_csr<<<spmm_blocks, TPB, 0, stream>>>(Y, row_ptr, row_cnt, A, B);
    lgcn_spmm_csr<<<spmm_blocks, TPB, 0, stream>>>(Y, row_ptr, row_cnt, B, C);
    lgcn_spmm_sampled<<<samp_blocks, TPB, 0, stream>>>(Y, row_ptr, row_cnt, C,
                                                       users, items, e3);

    // gamma
    lgcn_dot<<<dot_blocks, TPB, 0, stream>>>(user_emb, item_emb, B, C, e3,
                                             users, items, out);
}

// Round 7
// 483.716 us; speedup vs baseline: 11.4079x; 1.0765x over previous
//
#include <hip/hip_runtime.h>
#include <hip/hip_bf16.h>

// LightGCN forward on MI355X — round 16.
// r15 post-mortem: spmm VALU 53->41% but SAME 105us — NOT issue-bound; it's
//   gather-latency or L3-BW bound (VALU 43us + HBM 56us ~= 105us sum, no
//   overlap). FETCH unchanged 355MB.
// r16: (a) spmm inner unroll 8->16 edges (8 gathers in flight vs 4) — MLP
//   probe: latency-bound -> ~88us; L3-BW-bound -> unchanged.
//   (b) scatter1/scatter2 rewritten as block-local LDS counting-sort +
//   COALESCED per-bucket flush (register-staged input, read-once). Kills the
//   scattered-8B-store retirement cost that r11/r13 measured (4x write amp).
//   WRITE_SIZE predicted ~52-56MB per scatter.

#define N_USERS  100000
#define N_ITEMS  50000
#define N_TOTAL  150000          // N_USERS + N_ITEMS
#define D        64
#define NNZ      6400000
#define BATCH    4096
#define NELEM    (N_TOTAL * D)   // 9,600,000

#define NC       37              // coarse buckets (4096 rows each)
#define CROWS    4096
#define CAPC     194600          // coarse capacity (mean 174763 + 48 sigma);
                                 // also sized so X >= A+B+C (57.6MB aliasing)
#define S1C      4096            // scatter1 chunk (fits 32KB LDS stage)
#define S1EB     ((NNZ + S1C - 1) / S1C)       // 1563
#define S2C      4096
#define NCH2     ((CAPC + S2C - 1) / S2C)      // 48 chunks per coarse region
#define NF       64              // fine buckets per coarse (64 rows each)
#define RPB      64
#define NBUK     (NC * NF)       // 2368 fine buckets
#define CAPF     3456            // fine capacity = mean 2731 + 14 sigma

__device__ __forceinline__ float bf2f(unsigned short h) {
    return __uint_as_float(((unsigned int)h) << 16);
}

// ---------- zero cursors ----------
__global__ void lgcn_zero(int* __restrict__ cur1, int* __restrict__ cur2) {
    int i = threadIdx.x;
    if (i < NC) cur1[i] = 0;
    for (int j = i; j < NBUK; j += 256) cur2[j] = 0;
}

// ---------- pass 1: COO -> 37 coarse buckets, LDS sort + coalesced flush ----
// X pair: x = (row_in_coarse<<18) | col  (12b + 18b), y = val bits
__global__ void __launch_bounds__(256)
lgcn_scatter1(const int*   __restrict__ rows,
              const int*   __restrict__ cols,
              const float* __restrict__ vals,
              int*         __restrict__ cur1,
              int2*        __restrict__ X) {
    __shared__ int2 buf[S1C];              // 32 KB
    __shared__ unsigned char bk[S1C];      // 4 KB (bucket of slot)
    __shared__ int h[NC], ls[NC], gb[NC];
    int tid = threadIdx.x;
    int s = blockIdx.x * S1C;
    int n = NNZ - s; if (n > S1C) n = S1C;
    int r[16];

    if (tid < NC) h[tid] = 0;
    __syncthreads();
    #pragma unroll
    for (int k = 0; k < 16; k++) {         // coalesced load + histogram
        int i = tid + k * 256;
        r[k] = (i < n) ? rows[s + i] : -1;
        if (r[k] >= 0) atomicAdd(&h[r[k] >> 12], 1);
    }
    __syncthreads();
    if (tid == 0) {                        // serial scan over 37 buckets
        int acc = 0;
        for (int i = 0; i < NC; i++) { ls[i] = acc; acc += h[i]; }
    }
    if (tid < NC) gb[tid] = h[tid] ? atomicAdd(&cur1[tid], h[tid]) : 0;
    __syncthreads();
    if (tid < NC) h[tid] = 0;              // reuse as local cursor
    __syncthreads();
    #pragma unroll
    for (int k = 0; k < 16; k++) {         // place into bucket-ordered LDS
        int i = tid + k * 256;
        if (r[k] >= 0) {
            int c = r[k] >> 12;
            int rank = atomicAdd(&h[c], 1);
            int slot = ls[c] + rank;
            int2 p;
            p.x = ((r[k] & 4095) << 18) | cols[s + i];
            p.y = __float_as_int(vals[s + i]);
            buf[slot] = p;
            bk[slot] = (unsigned char)c;
        }
    }
    __syncthreads();
    for (int j = tid; j < n; j += 256) {   // coalesced flush (runs ~110 entries)
        int c = bk[j];
        int o = gb[c] + j - ls[c];
        X[(o < CAPC) ? ((size_t)c * CAPC + o) : ((size_t)NC * CAPC)] = buf[j];
    }
}

// ---------- pass 2: coarse -> 64 fine buckets, LDS sort + coalesced flush ----
// Y pair: x = (col18 << 7) | lr6  (pre-scaled column: x & ~127 = row byte off)
__global__ void __launch_bounds__(256)
lgcn_scatter2(const int2* __restrict__ X,
              const int*  __restrict__ cur1,
              int*        __restrict__ cur2,
              int2*       __restrict__ Y) {
    __shared__ int2 buf[S2C];              // 32 KB
    __shared__ unsigned char bk[S2C];      // 4 KB
    __shared__ int h[NF], ls[NF], gb[NF];
    int c = blockIdx.x / NCH2;
    int ch = blockIdx.x % NCH2;
    int cnt_c = cur1[c]; if (cnt_c > CAPC) cnt_c = CAPC;
    int s = ch * S2C;
    int n = cnt_c - s; if (n > S2C) n = S2C;
    if (n <= 0) return;                    // uniform per block
    int tid = threadIdx.x;
    size_t base = (size_t)c * CAPC + s;
    int2 e[16];

    if (tid < NF) h[tid] = 0;
    __syncthreads();
    #pragma unroll
    for (int k = 0; k < 16; k++) {         // register-stage + histogram
        int i = tid + k * 256;
        if (i < n) {
            e[k] = X[base + i];
            atomicAdd(&h[e[k].x >> 24], 1);   // fine6 = lr12 >> 6
        } else e[k].x = -1;                   // x >= 0 for valid (30-bit)
    }
    __syncthreads();
    if (tid == 0) {
        int acc = 0;
        for (int i = 0; i < NF; i++) { ls[i] = acc; acc += h[i]; }
    }
    if (tid < NF) gb[tid] = h[tid] ? atomicAdd(&cur2[c * NF + tid], h[tid]) : 0;
    __syncthreads();
    if (tid < NF) h[tid] = 0;
    __syncthreads();
    #pragma unroll
    for (int k = 0; k < 16; k++) {
        if (e[k].x >= 0) {
            int f = e[k].x >> 24;
            int rank = atomicAdd(&h[f], 1);
            int slot = ls[f] + rank;
            int2 q;
            q.x = ((e[k].x & 0x3FFFF) << 7) | ((e[k].x >> 18) & 63);  // col<<7|lr6
            q.y = e[k].y;
            buf[slot] = q;
            bk[slot] = (unsigned char)f;
        }
    }
    __syncthreads();
    for (int j = tid; j < n; j += 256) {   // coalesced flush (runs ~64 entries)
        int f = bk[j];
        int o = gb[f] + j - ls[f];
        Y[(o < CAPF) ? ((size_t)(c * NF + f) * CAPF + o)
                     : ((size_t)NBUK * CAPF)] = buf[j];
    }
}

// ---------- pass 3: in-place per-fine-bucket row-exact sort; emit CSR ----------
__global__ void __launch_bounds__(256)
lgcn_bucket_sort(int2* __restrict__ Y,
                 const int* __restrict__ cur2,
                 int* __restrict__ row_ptr,
                 int* __restrict__ row_cnt) {
    __shared__ int2 buf[CAPF];         // 27.6 KB -> 5 blocks/CU
    __shared__ int  h[RPB];
    __shared__ int  base[RPB];
    int tid = threadIdx.x;
    int fb = blockIdx.x;
    size_t start = (size_t)fb * CAPF;
    int cnt = cur2[fb]; if (cnt > CAPF) cnt = CAPF;

    for (int i = tid; i < cnt; i += 256) buf[i] = Y[start + i];
    if (tid < RPB) h[tid] = 0;
    __syncthreads();
    for (int i = tid; i < cnt; i += 256) atomicAdd(&h[buf[i].x & 63], 1);
    __syncthreads();

    // exclusive scan of h[0..63]
    int v = (tid < RPB) ? h[tid] : 0;
    int sum = v;
    #pragma unroll
    for (int off = 1; off < RPB; off <<= 1) {
        if (tid < RPB) base[tid] = sum;
        __syncthreads();
        if (tid >= off && tid < RPB) sum += base[tid - off];
        __syncthreads();
    }
    if (tid < RPB) {
        int excl = sum - v;
        base[tid] = excl;
        int gr = (fb >> 6) * CROWS + (fb & 63) * RPB + tid;
        if (gr < N_TOTAL) {
            row_ptr[gr] = (int)start + excl;
            row_cnt[gr] = v;
        }
        h[tid] = 0;                    // reuse as per-row cursor
    }
    __syncthreads();

    for (int i = tid; i < cnt; i += 256) {
        int2 p = buf[i];
        int lr = p.x & 63;
        int rank = atomicAdd(&h[lr], 1);
        Y[start + base[lr] + rank] = p;   // in place; 27KB window -> L2
    }
}

// ---------- init A = bf16(concat(user,item)) (after pass 2: A aliases X) ------
__global__ void lgcn_init_A(const float* __restrict__ user_emb,
                            const float* __restrict__ item_emb,
                            unsigned short* __restrict__ A) {
    int i = blockIdx.x * blockDim.x + threadIdx.x;
    if (i < NELEM) {
        float v = (i < N_USERS * D) ? user_emb[i] : item_emb[i - N_USERS * D];
        __hip_bfloat16 b = __float2bfloat16(v);   // RNE
        A[i] = *(unsigned short*)&b;
    }
}

// ---------- SpMM: wave per row, dual-edge, LDS-staged, 16-edge unroll ----------
// Pair chunk staged in per-wave LDS slice (512B); dual-edge reads via
// ds_read_b64 at immediate offsets. x & ~127 = table row byte off; per-lane
// +hl*4 folded into base pointer. Beyond-cnt entries are {0,0} -> v=0.
// 8 gathers in flight per body (MLP probe).
__global__ void __launch_bounds__(256)
lgcn_spmm_csr(const int2* __restrict__ pairs,
              const int*  __restrict__ row_ptr,
              const int*  __restrict__ row_cnt,
              const unsigned short* __restrict__ cur,
              unsigned short* __restrict__ nxt) {
    __shared__ int2 stage[4][64];
    int t = blockIdx.x * blockDim.x + threadIdx.x;
    int r = t >> 6;
    int lane = t & 63;
    if (r >= N_TOTAL) return;
    int halfid = lane >> 5;
    int hl = lane & 31;
    const char* __restrict__ curb = (const char*)cur + hl * 4;  // lane-folded
    int2* st = stage[threadIdx.x >> 6];
    int start = row_ptr[r];
    int cnt   = row_cnt[r];
    float sA = 0.f, sB = 0.f;
    for (int base = 0; base < cnt; base += 64) {
        int idx = base + lane;
        int2 p = {0, 0};
        if (idx < cnt) p = pairs[start + idx];     // coalesced dwordx2
        st[lane] = p;                              // per-wave slice, no barrier
        int m = cnt - base; if (m > 64) m = 64;
        for (int jj = 0; jj < m; jj += 16) {       // 16 edges per body
            #pragma unroll
            for (int k = 0; k < 8; k++) {
                int2 q = st[jj + 2 * k + halfid];  // ds_read_b64 broadcast
                float v = __int_as_float(q.y);     // 0 beyond cnt
                unsigned off = (unsigned)q.x & 0xFFFFFF80u;   // col*128
                unsigned u = *(const unsigned*)(curb + off);
                sA = fmaf(v, __uint_as_float(u << 16), sA);
                sB = fmaf(v, __uint_as_float(u & 0xFFFF0000u), sB);
            }
        }
    }
    sA += __shfl_xor(sA, 32, 64);
    sB += __shfl_xor(sB, 32, 64);
    if (halfid == 0) {
        __hip_bfloat16 a = __float2bfloat16(sA);   // RNE
        __hip_bfloat16 b = __float2bfloat16(sB);
        unsigned int lo = *(unsigned short*)&a;
        unsigned int hi = *(unsigned short*)&b;
        ((unsigned int*)nxt)[r * 32 + hl] = lo | (hi << 16);  // half-wave 128B
    }
}

// ---------- layer 3 at sampled rows only: e3[s,:] = (A @ E2)[row(s),:] (f32) ----
__global__ void __launch_bounds__(256)
lgcn_spmm_sampled(const int2* __restrict__ pairs,
                  const int*  __restrict__ row_ptr,
                  const int*  __restrict__ row_cnt,
                  const unsigned short* __restrict__ cur,
                  const int* __restrict__ users,
                  const int* __restrict__ items,
                  float* __restrict__ e3) {
    __shared__ int2 stage[4][64];
    int t = blockIdx.x * blockDim.x + threadIdx.x;
    int s = t >> 6;
    int lane = t & 63;
    if (s >= 2 * BATCH) return;
    int r = (s < BATCH) ? users[s] : (N_USERS + items[s - BATCH]);
    const char* __restrict__ curb = (const char*)cur + lane * 2;  // bf16 dim
    int2* st = stage[threadIdx.x >> 6];
    int start = row_ptr[r];
    int cnt   = row_cnt[r];
    float sum0 = 0.f, sum1 = 0.f;
    for (int base = 0; base < cnt; base += 64) {
        int idx = base + lane;
        int2 p = {0, 0};
        if (idx < cnt) p = pairs[start + idx];
        st[lane] = p;
        int m = cnt - base; if (m > 64) m = 64;
        for (int j = 0; j < m; j += 16) {
            #pragma unroll
            for (int k = 0; k < 16; k++) {
                int2 q = st[j + k];                // broadcast
                float v = __int_as_float(q.y);     // 0 beyond cnt
                unsigned off = (unsigned)q.x & 0xFFFFFF80u;
                unsigned short u = *(const unsigned short*)(curb + off);
                if (k & 1) sum1 = fmaf(v, bf2f(u), sum1);
                else       sum0 = fmaf(v, bf2f(u), sum0);
            }
        }
    }
    e3[s * D + lane] = sum0 + sum1;
}

// ---------- dot: gamma = <E0+E1+E2+E3>_u . <E0+E1+E2+E3>_i / 16 ----------
__global__ void lgcn_dot(const float* __restrict__ user_emb,
                         const float* __restrict__ item_emb,
                         const unsigned short* __restrict__ E1,
                         const unsigned short* __restrict__ E2,
                         const float* __restrict__ e3,
                         const int* __restrict__ users,
                         const int* __restrict__ items,
                         float* __restrict__ out) {
    int t = blockIdx.x * blockDim.x + threadIdx.x;
    int b = t >> 6;
    int d = t & 63;
    if (b < BATCH) {
        int u  = users[b];
        int it = items[b];
        int ur = u * D + d;
        int ir = (N_USERS + it) * D + d;
        float au = user_emb[ur] + bf2f(E1[ur]) + bf2f(E2[ur]) + e3[b * D + d];
        float ai = item_emb[it * D + d] + bf2f(E1[ir]) + bf2f(E2[ir])
                 + e3[(BATCH + b) * D + d];
        float p = au * ai;
        #pragma unroll
        for (int off = 32; off; off >>= 1) p += __shfl_down(p, off, 64);
        if (d == 0) out[b] = p * (1.0f / 16.0f);
    }
}

// ---------- round-1 fallback (atomic scatter) if ws too small ----------
__global__ void lgcn_init_fb(const float* __restrict__ user_emb,
                             const float* __restrict__ item_emb,
                             float* __restrict__ acc,
                             float* __restrict__ cur,
                             float* __restrict__ nxt) {
    int i = blockIdx.x * blockDim.x + threadIdx.x;
    if (i < NELEM) {
        float v = (i < N_USERS * D) ? user_emb[i] : item_emb[i - N_USERS * D];
        acc[i] = v; cur[i] = v; nxt[i] = 0.0f;
    }
}
__global__ void lgcn_spmm_fb(const int* __restrict__ rows,
                             const int* __restrict__ cols,
                             const float* __restrict__ vals,
                             const float* __restrict__ cur,
                             float* __restrict__ nxt) {
    long long t = (long long)blockIdx.x * blockDim.x + threadIdx.x;
    int e = (int)(t >> 6);
    int d = (int)(t & 63);
    if (e < NNZ) {
        float x = cur[cols[e] * D + d];
        unsafeAtomicAdd(&nxt[rows[e] * D + d], vals[e] * x);
    }
}
__global__ void lgcn_accum_fb(float* __restrict__ acc,
                              const float* __restrict__ src,
                              float* __restrict__ to_zero) {
    int i = blockIdx.x * blockDim.x + threadIdx.x;
    if (i < NELEM) {
        acc[i] += src[i];
        if (to_zero) to_zero[i] = 0.0f;
    }
}
__global__ void lgcn_dot_fb(const float* __restrict__ acc,
                            const int* __restrict__ users,
                            const int* __restrict__ items,
                            float* __restrict__ out) {
    int t = blockIdx.x * blockDim.x + threadIdx.x;
    int b = t >> 6;
    int d = t & 63;
    if (b < BATCH) {
        int u  = users[b];
        int it = items[b];
        float p = acc[u * D + d] * acc[(N_USERS + it) * D + d];
        #pragma unroll
        for (int off = 32; off; off >>= 1) p += __shfl_down(p, off, 64);
        if (d == 0) out[b] = p * (1.0f / 16.0f);
    }
}

extern "C" void kernel_launch(void* const* d_in, const int* in_sizes, int n_in,
                              void* d_out, int out_size, void* d_ws, size_t ws_size,
                              hipStream_t stream) {
    const float* user_emb = (const float*)d_in[0];
    const float* item_emb = (const float*)d_in[1];
    const int*   edge_row = (const int*)d_in[2];
    const int*   edge_col = (const int*)d_in[3];
    const float* edge_val = (const float*)d_in[4];
    const int*   users    = (const int*)d_in[5];
    const int*   items    = (const int*)d_in[6];
    float*       out      = (float*)d_out;

    const int TPB = 256;
    int init_blocks = (NELEM + TPB - 1) / TPB;
    int spmm_blocks = (N_TOTAL * 64 + TPB - 1) / TPB;       // wave per row
    int samp_blocks = (2 * BATCH * 64 + TPB - 1) / TPB;     // wave per sampled row
    int dot_blocks  = (BATCH * 64 + TPB - 1) / TPB;

    // workspace layout (~126.4MB, proven passing):
    //   X (coarse pairs, +1 sink) — dead after pass 2; A,B,C bf16 ALL alias it
    //     (CAPC sized so X bytes >= 3*NELEM*2 = 57.6MB)
    //   Y (fine pairs, +1 sink)   — final row-sorted CSR pairs (in-place sort)
    //   e3 f32, cursors, row_ptr/row_cnt
    int2* X = (int2*)d_ws;                              // NC*CAPC + 1
    int2* Y = X + (size_t)NC * CAPC + 1;                // NBUK*CAPF + 1
    float* e3 = (float*)(Y + (size_t)NBUK * CAPF + 1);  // 2*BATCH*D
    int* cur1 = (int*)(e3 + 2 * BATCH * D);             // NC
    int* cur2 = cur1 + NC;                              // NBUK
    int* row_ptr = cur2 + NBUK;                         // NBUK*RPB
    int* row_cnt = row_ptr + NBUK * RPB;                // NBUK*RPB
    size_t req = (size_t)((char*)(row_cnt + NBUK * RPB) - (char*)d_ws);
    unsigned short* A = (unsigned short*)X;             // alias: init after pass 2
    unsigned short* B = A + NELEM;                      // alias
    unsigned short* C = B + NELEM;                      // alias: 57.6MB <= X bytes

    if (ws_size < req && ws_size >= (size_t)3 * NELEM * 4) {
        // fallback: round-1 atomic path (needs only 3*NELEM floats)
        float* acc = (float*)d_ws;
        float* Af  = acc + NELEM;
        float* Bf  = Af + NELEM;
        long long st = (long long)NNZ * 64;
        int sb = (int)((st + TPB - 1) / TPB);
        lgcn_init_fb<<<init_blocks, TPB, 0, stream>>>(user_emb, item_emb, acc, Af, Bf);
        lgcn_spmm_fb<<<sb, TPB, 0, stream>>>(edge_row, edge_col, edge_val, Af, Bf);
        lgcn_accum_fb<<<init_blocks, TPB, 0, stream>>>(acc, Bf, Af);
        lgcn_spmm_fb<<<sb, TPB, 0, stream>>>(edge_row, edge_col, edge_val, Bf, Af);
        lgcn_accum_fb<<<init_blocks, TPB, 0, stream>>>(acc, Af, Bf);
        lgcn_spmm_fb<<<sb, TPB, 0, stream>>>(edge_row, edge_col, edge_val, Af, Bf);
        lgcn_accum_fb<<<init_blocks, TPB, 0, stream>>>(acc, Bf, nullptr);
        lgcn_dot_fb<<<dot_blocks, TPB, 0, stream>>>(acc, users, items, out);
        return;
    }

    // two-level radix binning (LDS-sorted, coalesced flush) + in-place row sort
    lgcn_zero<<<1, TPB, 0, stream>>>(cur1, cur2);
    lgcn_scatter1<<<S1EB, TPB, 0, stream>>>(edge_row, edge_col, edge_val, cur1, X);
    lgcn_scatter2<<<NC * NCH2, TPB, 0, stream>>>(X, cur1, cur2, Y);
    lgcn_bucket_sort<<<NBUK, TPB, 0, stream>>>(Y, cur2, row_ptr, row_cnt);

    // E0 bf16 (A aliases dead X region)
    lgcn_init_A<<<init_blocks, TPB, 0, stream>>>(user_emb, item_emb, A);

    // layers 1,2 full width (bf16); layer 3 only at sampled rows (f32)
    lgcn_spmm_csr<<<spmm_blocks, TPB, 0, stream>>>(Y, row_ptr, row_cnt, A, B);
    lgcn_spmm_csr<<<spmm_blocks, TPB, 0, stream>>>(Y, row_ptr, row_cnt, B, C);
    lgcn_spmm_sampled<<<samp_blocks, TPB, 0, stream>>>(Y, row_ptr, row_cnt, C,
                                                       users, items, e3);

    // gamma
    lgcn_dot<<<dot_blocks, TPB, 0, stream>>>(user_emb, item_emb, B, C, e3,
                                             users, items, out);
}

// Round 8
// 465.102 us; speedup vs baseline: 11.8645x; 1.0400x over previous
//
#include <hip/hip_runtime.h>
#include <hip/hip_bf16.h>

// LightGCN forward on MI355X — round 17.
// r16 post-mortem: scatter counting-sort rewrite worked (-37us, scatters out
//   of top-5); spmm 16-edge unroll only -4.5% -> spmm is at a beyond-L2
//   traffic/latency wall (355MB @ 3.8TB/s ~= duration). Intra-spmm is spent.
// r17: fuse bucket_sort INTO spmm layer 1. Block per fine bucket: reg-stage
//   pairs + LDS histogram -> scan -> sorted placement in LDS -> emit
//   row_ptr/cnt -> coalesced sorted-Y writeback (for layer 2) -> compute
//   layer 1 from LDS pairs (wave owns 16 rows, dual-edge loop unchanged).
//   Deletes one kernel + one 51MB global pairs read. Layer 2 unchanged.

#define N_USERS  100000
#define N_ITEMS  50000
#define N_TOTAL  150000          // N_USERS + N_ITEMS
#define D        64
#define NNZ      6400000
#define BATCH    4096
#define NELEM    (N_TOTAL * D)   // 9,600,000

#define NC       37              // coarse buckets (4096 rows each)
#define CROWS    4096
#define CAPC     194600          // coarse capacity (mean 174763 + 48 sigma);
                                 // also sized so X >= A+B+C (57.6MB aliasing)
#define S1C      4096            // scatter1 chunk (fits 32KB LDS stage)
#define S1EB     ((NNZ + S1C - 1) / S1C)       // 1563
#define S2C      4096
#define NCH2     ((CAPC + S2C - 1) / S2C)      // 48 chunks per coarse region
#define NF       64              // fine buckets per coarse (64 rows each)
#define RPB      64
#define NBUK     (NC * NF)       // 2368 fine buckets
#define CAPF     3456            // fine capacity = mean 2731 + 14 sigma

__device__ __forceinline__ float bf2f(unsigned short h) {
    return __uint_as_float(((unsigned int)h) << 16);
}

// ---------- zero cursors ----------
__global__ void lgcn_zero(int* __restrict__ cur1, int* __restrict__ cur2) {
    int i = threadIdx.x;
    if (i < NC) cur1[i] = 0;
    for (int j = i; j < NBUK; j += 256) cur2[j] = 0;
}

// ---------- pass 1: COO -> 37 coarse buckets, LDS sort + coalesced flush ----
// X pair: x = (row_in_coarse<<18) | col  (12b + 18b), y = val bits
__global__ void __launch_bounds__(256)
lgcn_scatter1(const int*   __restrict__ rows,
              const int*   __restrict__ cols,
              const float* __restrict__ vals,
              int*         __restrict__ cur1,
              int2*        __restrict__ X) {
    __shared__ int2 buf[S1C];              // 32 KB
    __shared__ unsigned char bk[S1C];      // 4 KB (bucket of slot)
    __shared__ int h[NC], ls[NC], gb[NC];
    int tid = threadIdx.x;
    int s = blockIdx.x * S1C;
    int n = NNZ - s; if (n > S1C) n = S1C;
    int r[16];

    if (tid < NC) h[tid] = 0;
    __syncthreads();
    #pragma unroll
    for (int k = 0; k < 16; k++) {         // coalesced load + histogram
        int i = tid + k * 256;
        r[k] = (i < n) ? rows[s + i] : -1;
        if (r[k] >= 0) atomicAdd(&h[r[k] >> 12], 1);
    }
    __syncthreads();
    if (tid == 0) {                        // serial scan over 37 buckets
        int acc = 0;
        for (int i = 0; i < NC; i++) { ls[i] = acc; acc += h[i]; }
    }
    if (tid < NC) gb[tid] = h[tid] ? atomicAdd(&cur1[tid], h[tid]) : 0;
    __syncthreads();
    if (tid < NC) h[tid] = 0;              // reuse as local cursor
    __syncthreads();
    #pragma unroll
    for (int k = 0; k < 16; k++) {         // place into bucket-ordered LDS
        int i = tid + k * 256;
        if (r[k] >= 0) {
            int c = r[k] >> 12;
            int rank = atomicAdd(&h[c], 1);
            int slot = ls[c] + rank;
            int2 p;
            p.x = ((r[k] & 4095) << 18) | cols[s + i];
            p.y = __float_as_int(vals[s + i]);
            buf[slot] = p;
            bk[slot] = (unsigned char)c;
        }
    }
    __syncthreads();
    for (int j = tid; j < n; j += 256) {   // coalesced flush (runs ~110 entries)
        int c = bk[j];
        int o = gb[c] + j - ls[c];
        X[(o < CAPC) ? ((size_t)c * CAPC + o) : ((size_t)NC * CAPC)] = buf[j];
    }
}

// ---------- pass 2: coarse -> 64 fine buckets, LDS sort + coalesced flush ----
// Y pair: x = (col18 << 7) | lr6  (pre-scaled column: x & ~127 = row byte off)
__global__ void __launch_bounds__(256)
lgcn_scatter2(const int2* __restrict__ X,
              const int*  __restrict__ cur1,
              int*        __restrict__ cur2,
              int2*       __restrict__ Y) {
    __shared__ int2 buf[S2C];              // 32 KB
    __shared__ unsigned char bk[S2C];      // 4 KB
    __shared__ int h[NF], ls[NF], gb[NF];
    int c = blockIdx.x / NCH2;
    int ch = blockIdx.x % NCH2;
    int cnt_c = cur1[c]; if (cnt_c > CAPC) cnt_c = CAPC;
    int s = ch * S2C;
    int n = cnt_c - s; if (n > S2C) n = S2C;
    if (n <= 0) return;                    // uniform per block
    int tid = threadIdx.x;
    size_t base = (size_t)c * CAPC + s;
    int2 e[16];

    if (tid < NF) h[tid] = 0;
    __syncthreads();
    #pragma unroll
    for (int k = 0; k < 16; k++) {         // register-stage + histogram
        int i = tid + k * 256;
        if (i < n) {
            e[k] = X[base + i];
            atomicAdd(&h[e[k].x >> 24], 1);   // fine6 = lr12 >> 6
        } else e[k].x = -1;                   // x >= 0 for valid (30-bit)
    }
    __syncthreads();
    if (tid == 0) {
        int acc = 0;
        for (int i = 0; i < NF; i++) { ls[i] = acc; acc += h[i]; }
    }
    if (tid < NF) gb[tid] = h[tid] ? atomicAdd(&cur2[c * NF + tid], h[tid]) : 0;
    __syncthreads();
    if (tid < NF) h[tid] = 0;
    __syncthreads();
    #pragma unroll
    for (int k = 0; k < 16; k++) {
        if (e[k].x >= 0) {
            int f = e[k].x >> 24;
            int rank = atomicAdd(&h[f], 1);
            int slot = ls[f] + rank;
            int2 q;
            q.x = ((e[k].x & 0x3FFFF) << 7) | ((e[k].x >> 18) & 63);  // col<<7|lr6
            q.y = e[k].y;
            buf[slot] = q;
            bk[slot] = (unsigned char)f;
        }
    }
    __syncthreads();
    for (int j = tid; j < n; j += 256) {   // coalesced flush (runs ~64 entries)
        int f = bk[j];
        int o = gb[f] + j - ls[f];
        Y[(o < CAPF) ? ((size_t)(c * NF + f) * CAPF + o)
                     : ((size_t)NBUK * CAPF)] = buf[j];
    }
}

// ---------- init A = bf16(concat(user,item)) (after pass 2: A aliases X) ------
__global__ void lgcn_init_A(const float* __restrict__ user_emb,
                            const float* __restrict__ item_emb,
                            unsigned short* __restrict__ A) {
    int i = blockIdx.x * blockDim.x + threadIdx.x;
    if (i < NELEM) {
        float v = (i < N_USERS * D) ? user_emb[i] : item_emb[i - N_USERS * D];
        __hip_bfloat16 b = __float2bfloat16(v);   // RNE
        A[i] = *(unsigned short*)&b;
    }
}

// ---------- fused: per-bucket row sort + CSR emit + sorted-Y writeback +
//            SpMM layer 1 computed from LDS pairs (wave owns 16 rows) --------
__global__ void __launch_bounds__(256)
lgcn_spmm_sort(int2* __restrict__ Y,
               const int* __restrict__ cur2,
               int* __restrict__ row_ptr,
               int* __restrict__ row_cnt,
               const unsigned short* __restrict__ cur,
               unsigned short* __restrict__ nxt) {
    __shared__ int2 buf[CAPF + 2];     // 27.7 KB -> 5 blocks/CU
    __shared__ int  h[RPB];
    __shared__ int  base[RPB];
    int tid = threadIdx.x;
    int fb = blockIdx.x;
    size_t start = (size_t)fb * CAPF;
    int cnt = cur2[fb]; if (cnt > CAPF) cnt = CAPF;

    // register-stage load + per-row histogram
    int2 e[14];                        // ceil(3456/256) = 14
    if (tid < RPB) h[tid] = 0;
    __syncthreads();
    #pragma unroll
    for (int k = 0; k < 14; k++) {
        int i = tid + k * 256;
        if (i < cnt) {
            e[k] = Y[start + i];
            atomicAdd(&h[e[k].x & 63], 1);
        } else e[k].x = -1;            // valid x >= 0 (25-bit)
    }
    __syncthreads();

    // exclusive scan of h[0..63]
    int v = (tid < RPB) ? h[tid] : 0;
    int sum = v;
    #pragma unroll
    for (int off = 1; off < RPB; off <<= 1) {
        if (tid < RPB) base[tid] = sum;
        __syncthreads();
        if (tid >= off && tid < RPB) sum += base[tid - off];
        __syncthreads();
    }
    if (tid < RPB) {
        int excl = sum - v;
        base[tid] = excl;
        int gr = (fb >> 6) * CROWS + (fb & 63) * RPB + tid;
        if (gr < N_TOTAL) {
            row_ptr[gr] = (int)start + excl;
            row_cnt[gr] = v;
        }
        h[tid] = 0;                    // reuse as per-row cursor
    }
    __syncthreads();

    // place regs -> row-sorted LDS
    #pragma unroll
    for (int k = 0; k < 14; k++) {
        if (e[k].x >= 0) {
            int lr = e[k].x & 63;
            int rank = atomicAdd(&h[lr], 1);
            buf[base[lr] + rank] = e[k];
        }
    }
    __syncthreads();

    // coalesced sorted writeback (layer 2 reads this)
    for (int i = tid; i < cnt; i += 256) Y[start + i] = buf[i];

    // ---- SpMM layer 1 from LDS pairs: wave w owns rows w*16 .. w*16+15 ----
    int wave = tid >> 6, lane = tid & 63;
    int halfid = lane >> 5, hl = lane & 31;
    const char* __restrict__ curb = (const char*)cur + hl * 4;
    for (int lr = wave * 16; lr < wave * 16 + 16; lr++) {
        int rs = base[lr];
        int rc = h[lr];                // == row count after placement
        float sA = 0.f, sB = 0.f;
        int jj = 0;
        for (; jj + 8 <= rc; jj += 8) {            // unguarded dual-edge bodies
            #pragma unroll
            for (int k = 0; k < 4; k++) {
                int2 q = buf[rs + jj + 2 * k + halfid];   // ds_read broadcast
                float v2 = __int_as_float(q.y);
                unsigned off = (unsigned)q.x & 0xFFFFFF80u;
                unsigned u = *(const unsigned*)(curb + off);
                sA = fmaf(v2, __uint_as_float(u << 16), sA);
                sB = fmaf(v2, __uint_as_float(u & 0xFFFF0000u), sB);
            }
        }
        for (; jj < rc; jj += 2) {                 // guarded tail (<=4 iters)
            int2 q = buf[rs + jj + halfid];        // may overread 1 (padded)
            float v2 = __int_as_float(q.y);
            unsigned off = (unsigned)q.x & 0xFFFFFF80u;
            if (jj + halfid >= rc) { v2 = 0.f; off = 0; }
            unsigned u = *(const unsigned*)(curb + off);
            sA = fmaf(v2, __uint_as_float(u << 16), sA);
            sB = fmaf(v2, __uint_as_float(u & 0xFFFF0000u), sB);
        }
        sA += __shfl_xor(sA, 32, 64);
        sB += __shfl_xor(sB, 32, 64);
        int gr = (fb >> 6) * CROWS + (fb & 63) * RPB + lr;
        if (halfid == 0 && gr < N_TOTAL) {
            __hip_bfloat16 a = __float2bfloat16(sA);   // RNE
            __hip_bfloat16 b = __float2bfloat16(sB);
            unsigned int lo = *(unsigned short*)&a;
            unsigned int hi = *(unsigned short*)&b;
            ((unsigned int*)nxt)[gr * 32 + hl] = lo | (hi << 16);
        }
    }
}

// ---------- SpMM: wave per row, dual-edge, LDS-staged, 16-edge unroll ----------
__global__ void __launch_bounds__(256)
lgcn_spmm_csr(const int2* __restrict__ pairs,
              const int*  __restrict__ row_ptr,
              const int*  __restrict__ row_cnt,
              const unsigned short* __restrict__ cur,
              unsigned short* __restrict__ nxt) {
    __shared__ int2 stage[4][64];
    int t = blockIdx.x * blockDim.x + threadIdx.x;
    int r = t >> 6;
    int lane = t & 63;
    if (r >= N_TOTAL) return;
    int halfid = lane >> 5;
    int hl = lane & 31;
    const char* __restrict__ curb = (const char*)cur + hl * 4;  // lane-folded
    int2* st = stage[threadIdx.x >> 6];
    int start = row_ptr[r];
    int cnt   = row_cnt[r];
    float sA = 0.f, sB = 0.f;
    for (int base = 0; base < cnt; base += 64) {
        int idx = base + lane;
        int2 p = {0, 0};
        if (idx < cnt) p = pairs[start + idx];     // coalesced dwordx2
        st[lane] = p;                              // per-wave slice, no barrier
        int m = cnt - base; if (m > 64) m = 64;
        for (int jj = 0; jj < m; jj += 16) {       // 16 edges per body
            #pragma unroll
            for (int k = 0; k < 8; k++) {
                int2 q = st[jj + 2 * k + halfid];  // ds_read_b64 broadcast
                float v = __int_as_float(q.y);     // 0 beyond cnt
                unsigned off = (unsigned)q.x & 0xFFFFFF80u;   // col*128
                unsigned u = *(const unsigned*)(curb + off);
                sA = fmaf(v, __uint_as_float(u << 16), sA);
                sB = fmaf(v, __uint_as_float(u & 0xFFFF0000u), sB);
            }
        }
    }
    sA += __shfl_xor(sA, 32, 64);
    sB += __shfl_xor(sB, 32, 64);
    if (halfid == 0) {
        __hip_bfloat16 a = __float2bfloat16(sA);   // RNE
        __hip_bfloat16 b = __float2bfloat16(sB);
        unsigned int lo = *(unsigned short*)&a;
        unsigned int hi = *(unsigned short*)&b;
        ((unsigned int*)nxt)[r * 32 + hl] = lo | (hi << 16);  // half-wave 128B
    }
}

// ---------- layer 3 at sampled rows only: e3[s,:] = (A @ E2)[row(s),:] (f32) ----
__global__ void __launch_bounds__(256)
lgcn_spmm_sampled(const int2* __restrict__ pairs,
                  const int*  __restrict__ row_ptr,
                  const int*  __restrict__ row_cnt,
                  const unsigned short* __restrict__ cur,
                  const int* __restrict__ users,
                  const int* __restrict__ items,
                  float* __restrict__ e3) {
    __shared__ int2 stage[4][64];
    int t = blockIdx.x * blockDim.x + threadIdx.x;
    int s = t >> 6;
    int lane = t & 63;
    if (s >= 2 * BATCH) return;
    int r = (s < BATCH) ? users[s] : (N_USERS + items[s - BATCH]);
    const char* __restrict__ curb = (const char*)cur + lane * 2;  // bf16 dim
    int2* st = stage[threadIdx.x >> 6];
    int start = row_ptr[r];
    int cnt   = row_cnt[r];
    float sum0 = 0.f, sum1 = 0.f;
    for (int base = 0; base < cnt; base += 64) {
        int idx = base + lane;
        int2 p = {0, 0};
        if (idx < cnt) p = pairs[start + idx];
        st[lane] = p;
        int m = cnt - base; if (m > 64) m = 64;
        for (int j = 0; j < m; j += 16) {
            #pragma unroll
            for (int k = 0; k < 16; k++) {
                int2 q = st[j + k];                // broadcast
                float v = __int_as_float(q.y);     // 0 beyond cnt
                unsigned off = (unsigned)q.x & 0xFFFFFF80u;
                unsigned short u = *(const unsigned short*)(curb + off);
                if (k & 1) sum1 = fmaf(v, bf2f(u), sum1);
                else       sum0 = fmaf(v, bf2f(u), sum0);
            }
        }
    }
    e3[s * D + lane] = sum0 + sum1;
}

// ---------- dot: gamma = <E0+E1+E2+E3>_u . <E0+E1+E2+E3>_i / 16 ----------
__global__ void lgcn_dot(const float* __restrict__ user_emb,
                         const float* __restrict__ item_emb,
                         const unsigned short* __restrict__ E1,
                         const unsigned short* __restrict__ E2,
                         const float* __restrict__ e3,
                         const int* __restrict__ users,
                         const int* __restrict__ items,
                         float* __restrict__ out) {
    int t = blockIdx.x * blockDim.x + threadIdx.x;
    int b = t >> 6;
    int d = t & 63;
    if (b < BATCH) {
        int u  = users[b];
        int it = items[b];
        int ur = u * D + d;
        int ir = (N_USERS + it) * D + d;
        float au = user_emb[ur] + bf2f(E1[ur]) + bf2f(E2[ur]) + e3[b * D + d];
        float ai = item_emb[it * D + d] + bf2f(E1[ir]) + bf2f(E2[ir])
                 + e3[(BATCH + b) * D + d];
        float p = au * ai;
        #pragma unroll
        for (int off = 32; off; off >>= 1) p += __shfl_down(p, off, 64);
        if (d == 0) out[b] = p * (1.0f / 16.0f);
    }
}

// ---------- round-1 fallback (atomic scatter) if ws too small ----------
__global__ void lgcn_init_fb(const float* __restrict__ user_emb,
                             const float* __restrict__ item_emb,
                             float* __restrict__ acc,
                             float* __restrict__ cur,
                             float* __restrict__ nxt) {
    int i = blockIdx.x * blockDim.x + threadIdx.x;
    if (i < NELEM) {
        float v = (i < N_USERS * D) ? user_emb[i] : item_emb[i - N_USERS * D];
        acc[i] = v; cur[i] = v; nxt[i] = 0.0f;
    }
}
__global__ void lgcn_spmm_fb(const int* __restrict__ rows,
                             const int* __restrict__ cols,
                             const float* __restrict__ vals,
                             const float* __restrict__ cur,
                             float* __restrict__ nxt) {
    long long t = (long long)blockIdx.x * blockDim.x + threadIdx.x;
    int e = (int)(t >> 6);
    int d = (int)(t & 63);
    if (e < NNZ) {
        float x = cur[cols[e] * D + d];
        unsafeAtomicAdd(&nxt[rows[e] * D + d], vals[e] * x);
    }
}
__global__ void lgcn_accum_fb(float* __restrict__ acc,
                              const float* __restrict__ src,
                              float* __restrict__ to_zero) {
    int i = blockIdx.x * blockDim.x + threadIdx.x;
    if (i < NELEM) {
        acc[i] += src[i];
        if (to_zero) to_zero[i] = 0.0f;
    }
}
__global__ void lgcn_dot_fb(const float* __restrict__ acc,
                            const int* __restrict__ users,
                            const int* __restrict__ items,
                            float* __restrict__ out) {
    int t = blockIdx.x * blockDim.x + threadIdx.x;
    int b = t >> 6;
    int d = t & 63;
    if (b < BATCH) {
        int u  = users[b];
        int it = items[b];
        float p = acc[u * D + d] * acc[(N_USERS + it) * D + d];
        #pragma unroll
        for (int off = 32; off; off >>= 1) p += __shfl_down(p, off, 64);
        if (d == 0) out[b] = p * (1.0f / 16.0f);
    }
}

extern "C" void kernel_launch(void* const* d_in, const int* in_sizes, int n_in,
                              void* d_out, int out_size, void* d_ws, size_t ws_size,
                              hipStream_t stream) {
    const float* user_emb = (const float*)d_in[0];
    const float* item_emb = (const float*)d_in[1];
    const int*   edge_row = (const int*)d_in[2];
    const int*   edge_col = (const int*)d_in[3];
    const float* edge_val = (const float*)d_in[4];
    const int*   users    = (const int*)d_in[5];
    const int*   items    = (const int*)d_in[6];
    float*       out      = (float*)d_out;

    const int TPB = 256;
    int init_blocks = (NELEM + TPB - 1) / TPB;
    int spmm_blocks = (N_TOTAL * 64 + TPB - 1) / TPB;       // wave per row
    int samp_blocks = (2 * BATCH * 64 + TPB - 1) / TPB;     // wave per sampled row
    int dot_blocks  = (BATCH * 64 + TPB - 1) / TPB;

    // workspace layout (~126.4MB, proven passing):
    //   X (coarse pairs, +1 sink) — dead after pass 2; A,B,C bf16 ALL alias it
    //     (CAPC sized so X bytes >= 3*NELEM*2 = 57.6MB)
    //   Y (fine pairs, +1 sink)   — row-sorted in the fused kernel
    //   e3 f32, cursors, row_ptr/row_cnt
    int2* X = (int2*)d_ws;                              // NC*CAPC + 1
    int2* Y = X + (size_t)NC * CAPC + 1;                // NBUK*CAPF + 1
    float* e3 = (float*)(Y + (size_t)NBUK * CAPF + 1);  // 2*BATCH*D
    int* cur1 = (int*)(e3 + 2 * BATCH * D);             // NC
    int* cur2 = cur1 + NC;                              // NBUK
    int* row_ptr = cur2 + NBUK;                         // NBUK*RPB
    int* row_cnt = row_ptr + NBUK * RPB;                // NBUK*RPB
    size_t req = (size_t)((char*)(row_cnt + NBUK * RPB) - (char*)d_ws);
    unsigned short* A = (unsigned short*)X;             // alias: init after pass 2
    unsigned short* B = A + NELEM;                      // alias
    unsigned short* C = B + NELEM;                      // alias: 57.6MB <= X bytes

    if (ws_size < req && ws_size >= (size_t)3 * NELEM * 4) {
        // fallback: round-1 atomic path (needs only 3*NELEM floats)
        float* acc = (float*)d_ws;
        float* Af  = acc + NELEM;
        float* Bf  = Af + NELEM;
        long long st = (long long)NNZ * 64;
        int sb = (int)((st + TPB - 1) / TPB);
        lgcn_init_fb<<<init_blocks, TPB, 0, stream>>>(user_emb, item_emb, acc, Af, Bf);
        lgcn_spmm_fb<<<sb, TPB, 0, stream>>>(edge_row, edge_col, edge_val, Af, Bf);
        lgcn_accum_fb<<<init_blocks, TPB, 0, stream>>>(acc, Bf, Af);
        lgcn_spmm_fb<<<sb, TPB, 0, stream>>>(edge_row, edge_col, edge_val, Bf, Af);
        lgcn_accum_fb<<<init_blocks, TPB, 0, stream>>>(acc, Af, Bf);
        lgcn_spmm_fb<<<sb, TPB, 0, stream>>>(edge_row, edge_col, edge_val, Af, Bf);
        lgcn_accum_fb<<<init_blocks, TPB, 0, stream>>>(acc, Bf, nullptr);
        lgcn_dot_fb<<<dot_blocks, TPB, 0, stream>>>(acc, users, items, out);
        return;
    }

    // two-level radix binning (LDS-sorted, coalesced flush)
    lgcn_zero<<<1, TPB, 0, stream>>>(cur1, cur2);
    lgcn_scatter1<<<S1EB, TPB, 0, stream>>>(edge_row, edge_col, edge_val, cur1, X);
    lgcn_scatter2<<<NC * NCH2, TPB, 0, stream>>>(X, cur1, cur2, Y);

    // E0 bf16 (A aliases dead X region)
    lgcn_init_A<<<init_blocks, TPB, 0, stream>>>(user_emb, item_emb, A);

    // fused: row sort + CSR emit + sorted-Y writeback + layer 1 from LDS
    lgcn_spmm_sort<<<NBUK, TPB, 0, stream>>>(Y, cur2, row_ptr, row_cnt, A, B);

    // layer 2 full width (bf16); layer 3 only at sampled rows (f32)
    lgcn_spmm_csr<<<spmm_blocks, TPB, 0, stream>>>(Y, row_ptr, row_cnt, B, C);
    lgcn_spmm_sampled<<<samp_blocks, TPB, 0, stream>>>(Y, row_ptr, row_cnt, C,
                                                       users, items, e3);

    // gamma
    lgcn_dot<<<dot_blocks, TPB, 0, stream>>>(user_emb, item_emb, B, C, e3,
                                             users, items, out);
}